// Round 1
// 197.788 us; speedup vs baseline: 1.0118x; 1.0118x over previous
//
#include <hip/hip_runtime.h>
#include <hip/hip_bf16.h>
#include <stdint.h>

#define B_ 2
#define T_ 2048
#define C_ 1024
#define H_ 16
#define D_ 64

typedef __attribute__((ext_vector_type(8))) short short8;
typedef __attribute__((ext_vector_type(4))) float floatx4;

__device__ __forceinline__ float bf2f(uint16_t b) {
    return __uint_as_float(((uint32_t)b) << 16);
}
__device__ __forceinline__ uint16_t f2b(float f) {
    __hip_bfloat16 h = __float2bfloat16(f);  // RNE
    return *(uint16_t*)&h;
}
__device__ __forceinline__ void glds16(const uint16_t* g, uint16_t* l) {
    __builtin_amdgcn_global_load_lds(
        (const __attribute__((address_space(1))) uint32_t*)g,
        (__attribute__((address_space(3))) uint32_t*)l, 16, 0, 0);
}

// ---- canonicalize x: fp32 -> bf16 -----------------------------------------
__global__ void canon_x(const float* __restrict__ in, uint16_t* __restrict__ out,
                        int n) {
    int i = (blockIdx.x * 256 + threadIdx.x) * 4;
    if (i >= n) return;
    float4 v = *(const float4*)(in + i);
    out[i + 0] = f2b(v.x);
    out[i + 1] = f2b(v.y);
    out[i + 2] = f2b(v.z);
    out[i + 3] = f2b(v.w);
}

// ---- transpose + convert: in [R,W] fp32 -> out [W,R] bf16 -----------------
__global__ void transpose_conv(const float* __restrict__ in, uint16_t* __restrict__ out,
                               int R, int W) {
    __shared__ uint16_t tile[32][33];
    int tx = threadIdx.x, ty = threadIdx.y;
    int c0 = blockIdx.x * 32, r0 = blockIdx.y * 32;
    #pragma unroll
    for (int i = 0; i < 32; i += 8)
        tile[ty + i][tx] = f2b(in[(size_t)(r0 + ty + i) * W + (c0 + tx)]);
    __syncthreads();
    #pragma unroll
    for (int i = 0; i < 32; i += 8)
        out[(size_t)(c0 + ty + i) * R + (r0 + tx)] = tile[tx][ty + i];
}

// ------- GEMM: C[M,N] = A[M,K] @ Bt[N,K]^T ; bf16 in, fp32 acc -------------
// 2-phase double-buffered (T3-minimum): BK=64, issue next-tile global_load_lds
// BEFORE ds_read+MFMA of current tile, ONE barrier per K-step. LDS read uses
// XOR slot swizzle with pre-swizzled global source (both-sides, rule 21):
//   phys slot p at row r holds source k-slot p ^ (r&7); staging lane l writes
//   phys (row base+l/8, slot l%8) so its source slot is (l%8)^(l/8).
// Grid is 1D with bijective XCD swizzle (nwg % 8 == 0), A-panel-major.
template <bool OUT_F32>
__global__ __launch_bounds__(256, 2)
void gemm_bt(const uint16_t* __restrict__ A, const uint16_t* __restrict__ Bt,
             void* __restrict__ Cv, int M, int N, int K) {
    __shared__ uint16_t As[2][128][64];   // 32 KB
    __shared__ uint16_t Bs[2][128][64];   // 32 KB
    int tid = threadIdx.x;
    int w = tid >> 6, lane = tid & 63;
    int quad = lane >> 4, l16 = lane & 15;
    int wr = (w >> 1) * 64, wc = (w & 1) * 64;

    // T1: bijective XCD swizzle; consecutive wg share the A row-panel
    int nwg = gridDim.x;
    int wg = (blockIdx.x & 7) * (nwg >> 3) + (blockIdx.x >> 3);
    int nby = N >> 7;
    int row0 = (wg / nby) * 128;
    int col0 = (wg % nby) * 128;

    // staging map: wave-load j covers rows w*32+j*8 .. +8, lane l -> row l/8,
    // phys 16B-slot l%8; LDS dest is wave-base + lane*16 (contiguous, req'd)
    int sr = w * 32 + (lane >> 3);
    int gsc = ((lane & 7) ^ (lane >> 3)) * 8;     // swizzled SOURCE k-col
    uint16_t* lA = &As[0][sr][(lane & 7) * 8];
    uint16_t* lB = &Bs[0][sr][(lane & 7) * 8];
    const size_t LBUF = 128 * 64;                 // u16 elems per buffer
    const uint16_t* gA = A + (size_t)(row0 + sr) * K + gsc;
    const uint16_t* gB = Bt + (size_t)(col0 + sr) * K + gsc;

    floatx4 acc[4][4];
    #pragma unroll
    for (int i = 0; i < 4; i++)
        #pragma unroll
        for (int j = 0; j < 4; j++)
            acc[i][j] = (floatx4){0.f, 0.f, 0.f, 0.f};

#define STAGE_(buf, k0)                                                     \
    {                                                                       \
        _Pragma("unroll") for (int j = 0; j < 4; j++) {                     \
            glds16(gA + (size_t)j * 8 * K + (k0), lA + (buf)*LBUF + j * 8 * 64); \
            glds16(gB + (size_t)j * 8 * K + (k0), lB + (buf)*LBUF + j * 8 * 64); \
        }                                                                   \
    }

    int NT = K >> 6;                 // K=1024 -> 16 tiles
    STAGE_(0, 0);
    __syncthreads();                 // drains vmcnt(0): tile 0 resident

    for (int t = 0; t < NT; ++t) {
        int cur = t & 1;
        if (t + 1 < NT) STAGE_(cur ^ 1, (t + 1) << 6);   // lands under MFMA
        #pragma unroll
        for (int kk = 0; kk < 2; kk++) {
            // swizzled read slot: logical slot kk*4+quad, row&7 == l16&7
            int s = ((kk * 4 + quad) ^ (l16 & 7)) * 8;
            short8 af[4], bf[4];
            #pragma unroll
            for (int i = 0; i < 4; i++)
                af[i] = *(const short8*)&As[cur][wr + i * 16 + l16][s];
            #pragma unroll
            for (int j = 0; j < 4; j++)
                bf[j] = *(const short8*)&Bs[cur][wc + j * 16 + l16][s];
            #pragma unroll
            for (int i = 0; i < 4; i++)
                #pragma unroll
                for (int j = 0; j < 4; j++)
                    acc[i][j] = __builtin_amdgcn_mfma_f32_16x16x32_bf16(
                        af[i], bf[j], acc[i][j], 0, 0, 0);
        }
        __syncthreads();             // next-tile loads drained; cur readable->writable
    }
#undef STAGE_

    #pragma unroll
    for (int i = 0; i < 4; i++) {
        #pragma unroll
        for (int j = 0; j < 4; j++) {
            int rbase = row0 + wr + i * 16 + quad * 4;
            int cg = col0 + wc + j * 16 + l16;
            #pragma unroll
            for (int r = 0; r < 4; r++) {
                if (OUT_F32)
                    ((float*)Cv)[(size_t)(rbase + r) * N + cg] = acc[i][j][r];
                else
                    ((uint16_t*)Cv)[(size_t)(rbase + r) * N + cg] = f2b(acc[i][j][r]);
            }
        }
    }
}

// ---------------- MFMA flash attention with sink ---------------------------
// Pair-balanced: block (pair,bh) covers strips 31-pair (waves 0,1) and pair
// (waves 2,3); every block stages 32-pair ktiles, total work constant (33).
// 1D grid id = pair*32+bh so id%8 = bh%8 -> same-bh blocks share one XCD L2.
// Wave = 32 q rows (2 qt). Double-buffered K/V LDS, 1 barrier/ktile,
// register prefetch. S^T = K*Q^T; P via per-wave LDS; O += P*V.
__global__ __launch_bounds__(256, 2)
void attn_mfma(const uint16_t* __restrict__ qkv,
               const float* __restrict__ sink,
               uint16_t* __restrict__ y) {
    __shared__ uint16_t Ks[2][64][72];   // [buf][key][d]   18432 B
    __shared__ uint16_t Vt[2][64][72];   // [buf][d][key]   18432 B (swizzled)
    __shared__ uint16_t Pl[4][32][72];   // per-wave [q][key] 18432 B

    int tid = threadIdx.x;
    int w = tid >> 6, lane = tid & 63;
    int quad = lane >> 4, l16 = lane & 15;

    int id = blockIdx.x;
    int pair = id >> 5, bh = id & 31;
    int b = bh >> 4, h = bh & 15;
    int strip = (w < 2) ? (31 - pair) : pair;   // this wave's 64-q strip
    int q0w = strip * 64 + (w & 1) * 32;        // wave's first q row
    int ktiles = 32 - pair;                     // tiles staged by the block
    int myktiles = strip + 1;                   // tiles this wave computes

    const uint16_t* qkv_b = qkv + (size_t)b * T_ * 3072;

    // ---- Q fragments: 2 qt x 2 kd, pre-scaled by 1/8 (exact) ----
    short8 qf[2][2];
    #pragma unroll
    for (int qt = 0; qt < 2; qt++) {
        int qrow = q0w + qt * 16 + l16;
        #pragma unroll
        for (int kd = 0; kd < 2; kd++) {
            uint4 raw = *(const uint4*)(qkv_b + (size_t)qrow * 3072 + h * 64 +
                                        kd * 32 + quad * 8);
            const uint16_t* rp = (const uint16_t*)&raw;
            short8 f;
            #pragma unroll
            for (int j = 0; j < 8; j++)
                f[j] = (short)f2b(bf2f(rp[j]) * 0.125f);
            qf[qt][kd] = f;
        }
    }

    float m_s[2], l_s[2];
    m_s[0] = m_s[1] = sink[h];
    l_s[0] = l_s[1] = 1.0f;
    floatx4 acc_o[2][4];
    #pragma unroll
    for (int qt = 0; qt < 2; qt++)
        #pragma unroll
        for (int dt = 0; dt < 4; dt++)
            acc_o[qt][dt] = (floatx4){0.f, 0.f, 0.f, 0.f};

    // ---- staging map: thread (t2,dg): key rows 2t2,2t2+1, dims dg*8..+7 ----
    int t2 = tid >> 3;
    int dg = tid & 7;
    const uint16_t* kgp = qkv_b + 1024 + h * 64 + (size_t)(2 * t2) * 3072 + dg * 8;
    const uint16_t* vgp = kgp + 1024;
    int vcw = 2 * (t2 ^ (4 * dg));   // swizzled u16 col for V^T key-pair store

    uint4 kr0 = *(const uint4*)(kgp);
    uint4 kr1 = *(const uint4*)(kgp + 3072);
    uint4 vr0 = *(const uint4*)(vgp);
    uint4 vr1 = *(const uint4*)(vgp + 3072);
    // store tile 0 -> buf 0
    {
        *(uint4*)&Ks[0][2 * t2][dg * 8] = kr0;
        *(uint4*)&Ks[0][2 * t2 + 1][dg * 8] = kr1;
        const uint16_t* a0 = (const uint16_t*)&vr0;
        const uint16_t* a1 = (const uint16_t*)&vr1;
        #pragma unroll
        for (int j = 0; j < 8; j++)
            *(uint32_t*)&Vt[0][dg * 8 + j][vcw] =
                (uint32_t)a0[j] | ((uint32_t)a1[j] << 16);
    }
    if (ktiles > 1) {   // preload tile 1
        kr0 = *(const uint4*)(kgp + 64 * 3072);
        kr1 = *(const uint4*)(kgp + 64 * 3072 + 3072);
        vr0 = *(const uint4*)(vgp + 64 * 3072);
        vr1 = *(const uint4*)(vgp + 64 * 3072 + 3072);
    }
    __syncthreads();

    for (int kt = 0; kt < ktiles; kt++) {
        int cur = kt & 1;
        // ---- store prefetched tile kt+1 into the other buffer ----
        if (kt + 1 < ktiles) {
            *(uint4*)&Ks[cur ^ 1][2 * t2][dg * 8] = kr0;
            *(uint4*)&Ks[cur ^ 1][2 * t2 + 1][dg * 8] = kr1;
            const uint16_t* a0 = (const uint16_t*)&vr0;
            const uint16_t* a1 = (const uint16_t*)&vr1;
            #pragma unroll
            for (int j = 0; j < 8; j++)
                *(uint32_t*)&Vt[cur ^ 1][dg * 8 + j][vcw] =
                    (uint32_t)a0[j] | ((uint32_t)a1[j] << 16);
        }
        // ---- issue prefetch of tile kt+2 (lands during this iter) ----
        if (kt + 2 < ktiles) {
            size_t off = (size_t)(kt + 2) * 64 * 3072;
            kr0 = *(const uint4*)(kgp + off);
            kr1 = *(const uint4*)(kgp + off + 3072);
            vr0 = *(const uint4*)(vgp + off);
            vr1 = *(const uint4*)(vgp + off + 3072);
        }
        if (kt < myktiles) {
            // ---- K and V fragments (shared by both qt) ----
            short8 kf[4][2];
            #pragma unroll
            for (int rt = 0; rt < 4; rt++) {
                kf[rt][0] = *(const short8*)&Ks[cur][rt * 16 + l16][quad * 8];
                kf[rt][1] = *(const short8*)&Ks[cur][rt * 16 + l16][32 + quad * 8];
            }
            short8 vf[2][4];
            #pragma unroll
            for (int kb = 0; kb < 2; kb++)
                #pragma unroll
                for (int dt = 0; dt < 4; dt++) {
                    int d = dt * 16 + l16;
                    int col = 2 * (((kb * 16) + quad * 4) ^ (4 * (d >> 3)));
                    vf[kb][dt] = *(const short8*)&Vt[cur][d][col];
                }
            #pragma unroll
            for (int qt = 0; qt < 2; qt++) {
                // ---- S^T = K * Q^T : key = rt*16+quad*4+r, q = l16 ----
                floatx4 acc_s[4];
                #pragma unroll
                for (int rt = 0; rt < 4; rt++)
                    acc_s[rt] = (floatx4){0.f, 0.f, 0.f, 0.f};
                #pragma unroll
                for (int rt = 0; rt < 4; rt++) {
                    acc_s[rt] = __builtin_amdgcn_mfma_f32_16x16x32_bf16(
                        kf[rt][0], qf[qt][0], acc_s[rt], 0, 0, 0);
                    acc_s[rt] = __builtin_amdgcn_mfma_f32_16x16x32_bf16(
                        kf[rt][1], qf[qt][1], acc_s[rt], 0, 0, 0);
                }
                // ---- causal mask: only the strip-diagonal tile ----
                if (kt == strip) {
                    int qg = q0w + qt * 16 + l16;
                    #pragma unroll
                    for (int rt = 0; rt < 4; rt++) {
                        int kg = kt * 64 + rt * 16 + quad * 4;
                        #pragma unroll
                        for (int r = 0; r < 4; r++)
                            if (kg + r > qg) acc_s[rt][r] = -1e30f;
                    }
                }
                // ---- online softmax (q = l16; reduce across quads) ----
                float mx = -1e30f;
                #pragma unroll
                for (int rt = 0; rt < 4; rt++)
                    #pragma unroll
                    for (int r = 0; r < 4; r++) mx = fmaxf(mx, acc_s[rt][r]);
                mx = fmaxf(mx, __shfl_xor(mx, 16));
                mx = fmaxf(mx, __shfl_xor(mx, 32));
                float mnew = fmaxf(m_s[qt], mx);
                float alpha = __expf(m_s[qt] - mnew);
                m_s[qt] = mnew;
                float psum = 0.f;
                #pragma unroll
                for (int rt = 0; rt < 4; rt++) {
                    float p0 = __expf(acc_s[rt][0] - mnew);
                    float p1 = __expf(acc_s[rt][1] - mnew);
                    float p2 = __expf(acc_s[rt][2] - mnew);
                    float p3 = __expf(acc_s[rt][3] - mnew);
                    psum += (p0 + p1) + (p2 + p3);
                    uint2 pk;
                    pk.x = (uint32_t)f2b(p0) | ((uint32_t)f2b(p1) << 16);
                    pk.y = (uint32_t)f2b(p2) | ((uint32_t)f2b(p3) << 16);
                    *(uint2*)&Pl[w][qt * 16 + l16][rt * 16 + quad * 4] = pk;
                }
                psum += __shfl_xor(psum, 16);
                psum += __shfl_xor(psum, 32);
                l_s[qt] = l_s[qt] * alpha + psum;
                #pragma unroll
                for (int r = 0; r < 4; r++) {
                    float ar = __shfl(alpha, (lane & 48) | (quad * 4 + r));
                    #pragma unroll
                    for (int dt = 0; dt < 4; dt++) acc_o[qt][dt][r] *= ar;
                }
                // ---- O += P * V ----
                #pragma unroll
                for (int kb = 0; kb < 2; kb++) {
                    short8 pf = *(const short8*)&Pl[w][qt * 16 + l16][kb * 32 + quad * 8];
                    #pragma unroll
                    for (int dt = 0; dt < 4; dt++)
                        acc_o[qt][dt] = __builtin_amdgcn_mfma_f32_16x16x32_bf16(
                            pf, vf[kb][dt], acc_o[qt][dt], 0, 0, 0);
                }
            }
        }
        __syncthreads();
    }

    // ---- epilogue: normalize by l (per-q via in-quad shuffle), store bf16 --
    #pragma unroll
    for (int qt = 0; qt < 2; qt++) {
        #pragma unroll
        for (int r = 0; r < 4; r++) {
            float lr = __shfl(l_s[qt], (lane & 48) | (quad * 4 + r));
            float inv = 1.0f / lr;
            int qg = q0w + qt * 16 + quad * 4 + r;
            uint16_t* yp = y + (size_t)(b * T_ + qg) * 1024 + h * 64;
            #pragma unroll
            for (int dt = 0; dt < 4; dt++)
                yp[dt * 16 + l16] = f2b(acc_o[qt][dt][r] * inv);
        }
    }
}

extern "C" void kernel_launch(void* const* d_in, const int* in_sizes, int n_in,
                              void* d_out, int out_size, void* d_ws, size_t ws_size,
                              hipStream_t stream) {
    const float* x      = (const float*)d_in[0];  // [B,T,C] fp32
    const float* w_qkv  = (const float*)d_in[1];  // [C, 3HD] fp32
    const float* w_proj = (const float*)d_in[2];  // [HD, C] fp32
    const float* sink   = (const float*)d_in[3];  // [H] fp32
    float* out          = (float*)d_out;          // [B,T,C] fp32

    char* ws = (char*)d_ws;
    uint16_t* wt_qkv  = (uint16_t*)ws;                       // [3072,1024] 6.29 MB
    uint16_t* wt_proj = (uint16_t*)(ws + 6291456);           // [1024,1024] 2.10 MB
    uint16_t* x_c     = (uint16_t*)(ws + 8388608);           // [4096,1024] 8.39 MB
    uint16_t* qkv     = (uint16_t*)(ws + 16777216);          // [4096,3072] 25.17 MB
    uint16_t* yb      = (uint16_t*)(ws + 41943040);          // [4096,1024] 8.39 MB

    canon_x<<<4194304 / 1024, 256, 0, stream>>>(x, x_c, 4194304);
    transpose_conv<<<dim3(3072 / 32, 1024 / 32), dim3(32, 8), 0, stream>>>(
        w_qkv, wt_qkv, 1024, 3072);
    transpose_conv<<<dim3(1024 / 32, 1024 / 32), dim3(32, 8), 0, stream>>>(
        w_proj, wt_proj, 1024, 1024);

    // 1D grids, nwg % 8 == 0 (bijective XCD swizzle inside)
    gemm_bt<false><<<dim3(768), 256, 0, stream>>>(
        x_c, wt_qkv, qkv, 4096, 3072, 1024);

    // pair-balanced grid: id = pair*32 + bh  (id%8 == bh%8 -> XCD locality)
    attn_mfma<<<dim3(16 * 32), 256, 0, stream>>>(qkv, sink, yb);

    gemm_bt<true><<<dim3(256), 256, 0, stream>>>(
        yb, wt_proj, out, 4096, 1024, 1024);
}

// Round 2
// 196.283 us; speedup vs baseline: 1.0195x; 1.0077x over previous
//
#include <hip/hip_runtime.h>
#include <hip/hip_bf16.h>
#include <stdint.h>

#define B_ 2
#define T_ 2048
#define C_ 1024
#define H_ 16
#define D_ 64

typedef __attribute__((ext_vector_type(8))) short short8;
typedef __attribute__((ext_vector_type(4))) float floatx4;

__device__ __forceinline__ float bf2f(uint16_t b) {
    return __uint_as_float(((uint32_t)b) << 16);
}
__device__ __forceinline__ uint16_t f2b(float f) {
    __hip_bfloat16 h = __float2bfloat16(f);  // RNE
    return *(uint16_t*)&h;
}
__device__ __forceinline__ void glds16(const uint16_t* g, uint16_t* l) {
    __builtin_amdgcn_global_load_lds(
        (const __attribute__((address_space(1))) uint32_t*)g,
        (__attribute__((address_space(3))) uint32_t*)l, 16, 0, 0);
}

// ---- canonicalize x: fp32 -> bf16 -----------------------------------------
__global__ void canon_x(const float* __restrict__ in, uint16_t* __restrict__ out,
                        int n) {
    int i = (blockIdx.x * 256 + threadIdx.x) * 4;
    if (i >= n) return;
    float4 v = *(const float4*)(in + i);
    out[i + 0] = f2b(v.x);
    out[i + 1] = f2b(v.y);
    out[i + 2] = f2b(v.z);
    out[i + 3] = f2b(v.w);
}

// ---- transpose + convert: in [R,W] fp32 -> out [W,R] bf16 -----------------
__global__ void transpose_conv(const float* __restrict__ in, uint16_t* __restrict__ out,
                               int R, int W) {
    __shared__ uint16_t tile[32][33];
    int tx = threadIdx.x, ty = threadIdx.y;
    int c0 = blockIdx.x * 32, r0 = blockIdx.y * 32;
    #pragma unroll
    for (int i = 0; i < 32; i += 8)
        tile[ty + i][tx] = f2b(in[(size_t)(r0 + ty + i) * W + (c0 + tx)]);
    __syncthreads();
    #pragma unroll
    for (int i = 0; i < 32; i += 8)
        out[(size_t)(c0 + ty + i) * R + (r0 + tx)] = tile[tx][ty + i];
}

// ------- GEMM: C[M,N] = A[M,K] @ Bt[N,K]^T ; bf16 in, fp32 acc -------------
// Counted-vmcnt pipeline (T3+T4): BK=32, THREE LDS buffers (48 KB -> 3
// blocks/CU), depth-2 global_load_lds prefetch. Per K-step: issue STAGE(t+2),
// ds_read + MFMA tile t, then s_waitcnt vmcnt(4) (t+1 resident, t+2 still in
// flight) + RAW s_barrier -- never drain vmcnt to 0 in the main loop (m218).
// XOR slot swizzle (phys slot = quad ^ (row&3)) with pre-swizzled global
// source (both-sides rule): 8-way ds_read_b128 conflict -> 4-way.
// Grid 1D, bijective XCD swizzle (nwg % 8 == 0), A-panel-major.
template <bool OUT_F32>
__global__ __launch_bounds__(256, 3)
void gemm_bt(const uint16_t* __restrict__ A, const uint16_t* __restrict__ Bt,
             void* __restrict__ Cv, int M, int N, int K) {
    __shared__ uint16_t As[3][128][32];   // 24 KB
    __shared__ uint16_t Bs[3][128][32];   // 24 KB
    int tid = threadIdx.x;
    int w = tid >> 6, lane = tid & 63;
    int quad = lane >> 4, l16 = lane & 15;
    int wr = (w >> 1) * 64, wc = (w & 1) * 64;

    // T1: bijective XCD swizzle; consecutive wg share the A row-panel
    int nwg = gridDim.x;
    int wg = (blockIdx.x & 7) * (nwg >> 3) + (blockIdx.x >> 3);
    int nby = N >> 7;
    int row0 = (wg / nby) * 128;
    int col0 = (wg % nby) * 128;

    // staging map: wave w round j covers rows w*32+j*16 .. +16; lane l ->
    // row +(l>>2), phys 16B-slot l&3; LDS dest = base + lane*16 (contiguous).
    // source k-slot = (l&3) ^ (row&3)  (row&3 == (l>>2)&3)
    int sr = w * 32 + (lane >> 2);
    int gsc = ((lane & 3) ^ ((lane >> 2) & 3)) * 8;
    uint16_t* lA0 = &As[0][sr][(lane & 3) * 8];
    uint16_t* lB0 = &Bs[0][sr][(lane & 3) * 8];
    const uint16_t* gA = A + (size_t)(row0 + sr) * K + gsc;
    const uint16_t* gB = Bt + (size_t)(col0 + sr) * K + gsc;

    floatx4 acc[4][4];
    #pragma unroll
    for (int i = 0; i < 4; i++)
        #pragma unroll
        for (int j = 0; j < 4; j++)
            acc[i][j] = (floatx4){0.f, 0.f, 0.f, 0.f};

#define STAGE3_(bs_, t_)                                                    \
    {                                                                       \
        const uint16_t* ga_ = gA + (size_t)(t_) * 32;                       \
        const uint16_t* gb_ = gB + (size_t)(t_) * 32;                       \
        uint16_t* la_ = lA0 + (bs_) * 4096;                                 \
        uint16_t* lb_ = lB0 + (bs_) * 4096;                                 \
        glds16(ga_, la_);                                                   \
        glds16(ga_ + 16 * K, la_ + 512);                                    \
        glds16(gb_, lb_);                                                   \
        glds16(gb_ + 16 * K, lb_ + 512);                                    \
    }

    int NT = K >> 5;                 // K=1024 -> 32 tiles
    STAGE3_(0, 0);
    STAGE3_(1, 1);
    asm volatile("s_waitcnt vmcnt(4)" ::: "memory");   // tile 0 resident
    __builtin_amdgcn_s_barrier();

    const uint16_t* Ab = &As[0][0][0];
    const uint16_t* Bb = &Bs[0][0][0];
    int s = (quad ^ (l16 & 3)) * 8;  // swizzled read slot (loop-invariant)
    int bc = 0, bs = 2;
    for (int t = 0; t < NT; ++t) {
        if (t + 2 < NT) STAGE3_(bs, t + 2);
        __builtin_amdgcn_sched_barrier(0);   // pin stage issue before compute
        const uint16_t* Ac = Ab + bc * 4096;
        const uint16_t* Bc = Bb + bc * 4096;
        short8 af[4], bfr[4];
        #pragma unroll
        for (int i = 0; i < 4; i++)
            af[i] = *(const short8*)&Ac[(wr + i * 16 + l16) * 32 + s];
        #pragma unroll
        for (int j = 0; j < 4; j++)
            bfr[j] = *(const short8*)&Bc[(wc + j * 16 + l16) * 32 + s];
        #pragma unroll
        for (int i = 0; i < 4; i++)
            #pragma unroll
            for (int j = 0; j < 4; j++)
                acc[i][j] = __builtin_amdgcn_mfma_f32_16x16x32_bf16(
                    af[i], bfr[j], acc[i][j], 0, 0, 0);
        if (t + 2 < NT) {
            asm volatile("s_waitcnt vmcnt(4)" ::: "memory");  // t+1 resident
        } else {
            asm volatile("s_waitcnt vmcnt(0)" ::: "memory");  // tail drain
        }
        __builtin_amdgcn_s_barrier();
        bc = (bc == 2) ? 0 : bc + 1;
        bs = (bs == 2) ? 0 : bs + 1;
    }
#undef STAGE3_

    #pragma unroll
    for (int i = 0; i < 4; i++) {
        #pragma unroll
        for (int j = 0; j < 4; j++) {
            int rbase = row0 + wr + i * 16 + quad * 4;
            int cg = col0 + wc + j * 16 + l16;
            #pragma unroll
            for (int r = 0; r < 4; r++) {
                if (OUT_F32)
                    ((float*)Cv)[(size_t)(rbase + r) * N + cg] = acc[i][j][r];
                else
                    ((uint16_t*)Cv)[(size_t)(rbase + r) * N + cg] = f2b(acc[i][j][r]);
            }
        }
    }
}

// ---------------- MFMA flash attention with sink ---------------------------
// Pair-balanced: block (pair,bh) covers strips 31-pair (waves 0,1) and pair
// (waves 2,3); every block stages 32-pair ktiles, total work constant (33).
// 1D grid id = pair*32+bh so id%8 = bh%8 -> same-bh blocks share one XCD L2.
// Wave = 32 q rows (2 qt). Double-buffered K/V LDS, 1 barrier/ktile,
// register prefetch. S^T = K*Q^T; P via per-wave LDS; O += P*V.
__global__ __launch_bounds__(256, 2)
void attn_mfma(const uint16_t* __restrict__ qkv,
               const float* __restrict__ sink,
               uint16_t* __restrict__ y) {
    __shared__ uint16_t Ks[2][64][72];   // [buf][key][d]   18432 B
    __shared__ uint16_t Vt[2][64][72];   // [buf][d][key]   18432 B (swizzled)
    __shared__ uint16_t Pl[4][32][72];   // per-wave [q][key] 18432 B

    int tid = threadIdx.x;
    int w = tid >> 6, lane = tid & 63;
    int quad = lane >> 4, l16 = lane & 15;

    int id = blockIdx.x;
    int pair = id >> 5, bh = id & 31;
    int b = bh >> 4, h = bh & 15;
    int strip = (w < 2) ? (31 - pair) : pair;   // this wave's 64-q strip
    int q0w = strip * 64 + (w & 1) * 32;        // wave's first q row
    int ktiles = 32 - pair;                     // tiles staged by the block
    int myktiles = strip + 1;                   // tiles this wave computes

    const uint16_t* qkv_b = qkv + (size_t)b * T_ * 3072;

    // ---- Q fragments: 2 qt x 2 kd, pre-scaled by 1/8 (exact) ----
    short8 qf[2][2];
    #pragma unroll
    for (int qt = 0; qt < 2; qt++) {
        int qrow = q0w + qt * 16 + l16;
        #pragma unroll
        for (int kd = 0; kd < 2; kd++) {
            uint4 raw = *(const uint4*)(qkv_b + (size_t)qrow * 3072 + h * 64 +
                                        kd * 32 + quad * 8);
            const uint16_t* rp = (const uint16_t*)&raw;
            short8 f;
            #pragma unroll
            for (int j = 0; j < 8; j++)
                f[j] = (short)f2b(bf2f(rp[j]) * 0.125f);
            qf[qt][kd] = f;
        }
    }

    float m_s[2], l_s[2];
    m_s[0] = m_s[1] = sink[h];
    l_s[0] = l_s[1] = 1.0f;
    floatx4 acc_o[2][4];
    #pragma unroll
    for (int qt = 0; qt < 2; qt++)
        #pragma unroll
        for (int dt = 0; dt < 4; dt++)
            acc_o[qt][dt] = (floatx4){0.f, 0.f, 0.f, 0.f};

    // ---- staging map: thread (t2,dg): key rows 2t2,2t2+1, dims dg*8..+7 ----
    int t2 = tid >> 3;
    int dg = tid & 7;
    const uint16_t* kgp = qkv_b + 1024 + h * 64 + (size_t)(2 * t2) * 3072 + dg * 8;
    const uint16_t* vgp = kgp + 1024;
    int vcw = 2 * (t2 ^ (4 * dg));   // swizzled u16 col for V^T key-pair store

    uint4 kr0 = *(const uint4*)(kgp);
    uint4 kr1 = *(const uint4*)(kgp + 3072);
    uint4 vr0 = *(const uint4*)(vgp);
    uint4 vr1 = *(const uint4*)(vgp + 3072);
    // store tile 0 -> buf 0
    {
        *(uint4*)&Ks[0][2 * t2][dg * 8] = kr0;
        *(uint4*)&Ks[0][2 * t2 + 1][dg * 8] = kr1;
        const uint16_t* a0 = (const uint16_t*)&vr0;
        const uint16_t* a1 = (const uint16_t*)&vr1;
        #pragma unroll
        for (int j = 0; j < 8; j++)
            *(uint32_t*)&Vt[0][dg * 8 + j][vcw] =
                (uint32_t)a0[j] | ((uint32_t)a1[j] << 16);
    }
    if (ktiles > 1) {   // preload tile 1
        kr0 = *(const uint4*)(kgp + 64 * 3072);
        kr1 = *(const uint4*)(kgp + 64 * 3072 + 3072);
        vr0 = *(const uint4*)(vgp + 64 * 3072);
        vr1 = *(const uint4*)(vgp + 64 * 3072 + 3072);
    }
    __syncthreads();

    for (int kt = 0; kt < ktiles; kt++) {
        int cur = kt & 1;
        // ---- store prefetched tile kt+1 into the other buffer ----
        if (kt + 1 < ktiles) {
            *(uint4*)&Ks[cur ^ 1][2 * t2][dg * 8] = kr0;
            *(uint4*)&Ks[cur ^ 1][2 * t2 + 1][dg * 8] = kr1;
            const uint16_t* a0 = (const uint16_t*)&vr0;
            const uint16_t* a1 = (const uint16_t*)&vr1;
            #pragma unroll
            for (int j = 0; j < 8; j++)
                *(uint32_t*)&Vt[cur ^ 1][dg * 8 + j][vcw] =
                    (uint32_t)a0[j] | ((uint32_t)a1[j] << 16);
        }
        // ---- issue prefetch of tile kt+2 (lands during this iter) ----
        if (kt + 2 < ktiles) {
            size_t off = (size_t)(kt + 2) * 64 * 3072;
            kr0 = *(const uint4*)(kgp + off);
            kr1 = *(const uint4*)(kgp + off + 3072);
            vr0 = *(const uint4*)(vgp + off);
            vr1 = *(const uint4*)(vgp + off + 3072);
        }
        if (kt < myktiles) {
            // ---- K and V fragments (shared by both qt) ----
            short8 kf[4][2];
            #pragma unroll
            for (int rt = 0; rt < 4; rt++) {
                kf[rt][0] = *(const short8*)&Ks[cur][rt * 16 + l16][quad * 8];
                kf[rt][1] = *(const short8*)&Ks[cur][rt * 16 + l16][32 + quad * 8];
            }
            short8 vf[2][4];
            #pragma unroll
            for (int kb = 0; kb < 2; kb++)
                #pragma unroll
                for (int dt = 0; dt < 4; dt++) {
                    int d = dt * 16 + l16;
                    int col = 2 * (((kb * 16) + quad * 4) ^ (4 * (d >> 3)));
                    vf[kb][dt] = *(const short8*)&Vt[cur][d][col];
                }
            #pragma unroll
            for (int qt = 0; qt < 2; qt++) {
                // ---- S^T = K * Q^T : key = rt*16+quad*4+r, q = l16 ----
                floatx4 acc_s[4];
                #pragma unroll
                for (int rt = 0; rt < 4; rt++)
                    acc_s[rt] = (floatx4){0.f, 0.f, 0.f, 0.f};
                #pragma unroll
                for (int rt = 0; rt < 4; rt++) {
                    acc_s[rt] = __builtin_amdgcn_mfma_f32_16x16x32_bf16(
                        kf[rt][0], qf[qt][0], acc_s[rt], 0, 0, 0);
                    acc_s[rt] = __builtin_amdgcn_mfma_f32_16x16x32_bf16(
                        kf[rt][1], qf[qt][1], acc_s[rt], 0, 0, 0);
                }
                // ---- causal mask: only the strip-diagonal tile ----
                if (kt == strip) {
                    int qg = q0w + qt * 16 + l16;
                    #pragma unroll
                    for (int rt = 0; rt < 4; rt++) {
                        int kg = kt * 64 + rt * 16 + quad * 4;
                        #pragma unroll
                        for (int r = 0; r < 4; r++)
                            if (kg + r > qg) acc_s[rt][r] = -1e30f;
                    }
                }
                // ---- online softmax (q = l16; reduce across quads) ----
                float mx = -1e30f;
                #pragma unroll
                for (int rt = 0; rt < 4; rt++)
                    #pragma unroll
                    for (int r = 0; r < 4; r++) mx = fmaxf(mx, acc_s[rt][r]);
                mx = fmaxf(mx, __shfl_xor(mx, 16));
                mx = fmaxf(mx, __shfl_xor(mx, 32));
                float mnew = fmaxf(m_s[qt], mx);
                float alpha = __expf(m_s[qt] - mnew);
                m_s[qt] = mnew;
                float psum = 0.f;
                #pragma unroll
                for (int rt = 0; rt < 4; rt++) {
                    float p0 = __expf(acc_s[rt][0] - mnew);
                    float p1 = __expf(acc_s[rt][1] - mnew);
                    float p2 = __expf(acc_s[rt][2] - mnew);
                    float p3 = __expf(acc_s[rt][3] - mnew);
                    psum += (p0 + p1) + (p2 + p3);
                    uint2 pk;
                    pk.x = (uint32_t)f2b(p0) | ((uint32_t)f2b(p1) << 16);
                    pk.y = (uint32_t)f2b(p2) | ((uint32_t)f2b(p3) << 16);
                    *(uint2*)&Pl[w][qt * 16 + l16][rt * 16 + quad * 4] = pk;
                }
                psum += __shfl_xor(psum, 16);
                psum += __shfl_xor(psum, 32);
                l_s[qt] = l_s[qt] * alpha + psum;
                #pragma unroll
                for (int r = 0; r < 4; r++) {
                    float ar = __shfl(alpha, (lane & 48) | (quad * 4 + r));
                    #pragma unroll
                    for (int dt = 0; dt < 4; dt++) acc_o[qt][dt][r] *= ar;
                }
                // ---- O += P * V ----
                #pragma unroll
                for (int kb = 0; kb < 2; kb++) {
                    short8 pf = *(const short8*)&Pl[w][qt * 16 + l16][kb * 32 + quad * 8];
                    #pragma unroll
                    for (int dt = 0; dt < 4; dt++)
                        acc_o[qt][dt] = __builtin_amdgcn_mfma_f32_16x16x32_bf16(
                            pf, vf[kb][dt], acc_o[qt][dt], 0, 0, 0);
                }
            }
        }
        __syncthreads();
    }

    // ---- epilogue: normalize by l (per-q via in-quad shuffle), store bf16 --
    #pragma unroll
    for (int qt = 0; qt < 2; qt++) {
        #pragma unroll
        for (int r = 0; r < 4; r++) {
            float lr = __shfl(l_s[qt], (lane & 48) | (quad * 4 + r));
            float inv = 1.0f / lr;
            int qg = q0w + qt * 16 + quad * 4 + r;
            uint16_t* yp = y + (size_t)(b * T_ + qg) * 1024 + h * 64;
            #pragma unroll
            for (int dt = 0; dt < 4; dt++)
                yp[dt * 16 + l16] = f2b(acc_o[qt][dt][r] * inv);
        }
    }
}

extern "C" void kernel_launch(void* const* d_in, const int* in_sizes, int n_in,
                              void* d_out, int out_size, void* d_ws, size_t ws_size,
                              hipStream_t stream) {
    const float* x      = (const float*)d_in[0];  // [B,T,C] fp32
    const float* w_qkv  = (const float*)d_in[1];  // [C, 3HD] fp32
    const float* w_proj = (const float*)d_in[2];  // [HD, C] fp32
    const float* sink   = (const float*)d_in[3];  // [H] fp32
    float* out          = (float*)d_out;          // [B,T,C] fp32

    char* ws = (char*)d_ws;
    uint16_t* wt_qkv  = (uint16_t*)ws;                       // [3072,1024] 6.29 MB
    uint16_t* wt_proj = (uint16_t*)(ws + 6291456);           // [1024,1024] 2.10 MB
    uint16_t* x_c     = (uint16_t*)(ws + 8388608);           // [4096,1024] 8.39 MB
    uint16_t* qkv     = (uint16_t*)(ws + 16777216);          // [4096,3072] 25.17 MB
    uint16_t* yb      = (uint16_t*)(ws + 41943040);          // [4096,1024] 8.39 MB

    canon_x<<<4194304 / 1024, 256, 0, stream>>>(x, x_c, 4194304);
    transpose_conv<<<dim3(3072 / 32, 1024 / 32), dim3(32, 8), 0, stream>>>(
        w_qkv, wt_qkv, 1024, 3072);
    transpose_conv<<<dim3(1024 / 32, 1024 / 32), dim3(32, 8), 0, stream>>>(
        w_proj, wt_proj, 1024, 1024);

    // 1D grids, nwg % 8 == 0 (bijective XCD swizzle inside)
    gemm_bt<false><<<dim3(768), 256, 0, stream>>>(
        x_c, wt_qkv, qkv, 4096, 3072, 1024);

    // pair-balanced grid: id = pair*32 + bh  (id%8 == bh%8 -> XCD locality)
    attn_mfma<<<dim3(16 * 32), 256, 0, stream>>>(qkv, sink, yb);

    gemm_bt<true><<<dim3(256), 256, 0, stream>>>(
        yb, wt_proj, out, 4096, 1024, 1024);
}

// Round 3
// 187.091 us; speedup vs baseline: 1.0696x; 1.0491x over previous
//
#include <hip/hip_runtime.h>
#include <hip/hip_bf16.h>
#include <stdint.h>

#define B_ 2
#define T_ 2048
#define C_ 1024
#define H_ 16
#define D_ 64

typedef __attribute__((ext_vector_type(8))) short short8;
typedef __attribute__((ext_vector_type(4))) float floatx4;

__device__ __forceinline__ float bf2f(uint16_t b) {
    return __uint_as_float(((uint32_t)b) << 16);
}
__device__ __forceinline__ uint16_t f2b(float f) {
    __hip_bfloat16 h = __float2bfloat16(f);  // RNE
    return *(uint16_t*)&h;
}
__device__ __forceinline__ void glds16(const uint16_t* g, uint16_t* l) {
    __builtin_amdgcn_global_load_lds(
        (const __attribute__((address_space(1))) uint32_t*)g,
        (__attribute__((address_space(3))) uint32_t*)l, 16, 0, 0);
}

// ---- canonicalize x: fp32 -> bf16 -----------------------------------------
__global__ void canon_x(const float* __restrict__ in, uint16_t* __restrict__ out,
                        int n) {
    int i = (blockIdx.x * 256 + threadIdx.x) * 4;
    if (i >= n) return;
    float4 v = *(const float4*)(in + i);
    out[i + 0] = f2b(v.x);
    out[i + 1] = f2b(v.y);
    out[i + 2] = f2b(v.z);
    out[i + 3] = f2b(v.w);
}

// ---- transpose + convert: in [R,W] fp32 -> out [W,R] bf16 -----------------
__global__ void transpose_conv(const float* __restrict__ in, uint16_t* __restrict__ out,
                               int R, int W) {
    __shared__ uint16_t tile[32][33];
    int tx = threadIdx.x, ty = threadIdx.y;
    int c0 = blockIdx.x * 32, r0 = blockIdx.y * 32;
    #pragma unroll
    for (int i = 0; i < 32; i += 8)
        tile[ty + i][tx] = f2b(in[(size_t)(r0 + ty + i) * W + (c0 + tx)]);
    __syncthreads();
    #pragma unroll
    for (int i = 0; i < 32; i += 8)
        out[(size_t)(c0 + ty + i) * R + (r0 + tx)] = tile[tx][ty + i];
}

// ------- GEMM: C[M,N] = A[M,K] @ Bt[N,K]^T ; bf16 in, fp32 acc -------------
// Counted-vmcnt pipeline (T3+T4): BK=32, THREE LDS buffers (48 KB -> 3
// blocks/CU), depth-2 global_load_lds prefetch. Per K-step: issue STAGE(t+2),
// ds_read + MFMA tile t, then s_waitcnt vmcnt(4) (t+1 resident, t+2 still in
// flight) + RAW s_barrier -- never drain vmcnt to 0 in the main loop (m218).
// XOR slot swizzle (phys slot = quad ^ (row&3)) with pre-swizzled global
// source (both-sides rule): 8-way ds_read_b128 conflict -> 4-way.
// Grid 1D, bijective XCD swizzle (nwg % 8 == 0), A-panel-major.
template <bool OUT_F32>
__global__ __launch_bounds__(256, 3)
void gemm_bt(const uint16_t* __restrict__ A, const uint16_t* __restrict__ Bt,
             void* __restrict__ Cv, int M, int N, int K) {
    __shared__ uint16_t As[3][128][32];   // 24 KB
    __shared__ uint16_t Bs[3][128][32];   // 24 KB
    int tid = threadIdx.x;
    int w = tid >> 6, lane = tid & 63;
    int quad = lane >> 4, l16 = lane & 15;
    int wr = (w >> 1) * 64, wc = (w & 1) * 64;

    // T1: bijective XCD swizzle; consecutive wg share the A row-panel
    int nwg = gridDim.x;
    int wg = (blockIdx.x & 7) * (nwg >> 3) + (blockIdx.x >> 3);
    int nby = N >> 7;
    int row0 = (wg / nby) * 128;
    int col0 = (wg % nby) * 128;

    // staging map: wave w round j covers rows w*32+j*16 .. +16; lane l ->
    // row +(l>>2), phys 16B-slot l&3; LDS dest = base + lane*16 (contiguous).
    // source k-slot = (l&3) ^ (row&3)  (row&3 == (l>>2)&3)
    int sr = w * 32 + (lane >> 2);
    int gsc = ((lane & 3) ^ ((lane >> 2) & 3)) * 8;
    uint16_t* lA0 = &As[0][sr][(lane & 3) * 8];
    uint16_t* lB0 = &Bs[0][sr][(lane & 3) * 8];
    const uint16_t* gA = A + (size_t)(row0 + sr) * K + gsc;
    const uint16_t* gB = Bt + (size_t)(col0 + sr) * K + gsc;

    floatx4 acc[4][4];
    #pragma unroll
    for (int i = 0; i < 4; i++)
        #pragma unroll
        for (int j = 0; j < 4; j++)
            acc[i][j] = (floatx4){0.f, 0.f, 0.f, 0.f};

#define STAGE3_(bs_, t_)                                                    \
    {                                                                       \
        const uint16_t* ga_ = gA + (size_t)(t_) * 32;                       \
        const uint16_t* gb_ = gB + (size_t)(t_) * 32;                       \
        uint16_t* la_ = lA0 + (bs_) * 4096;                                 \
        uint16_t* lb_ = lB0 + (bs_) * 4096;                                 \
        glds16(ga_, la_);                                                   \
        glds16(ga_ + 16 * K, la_ + 512);                                    \
        glds16(gb_, lb_);                                                   \
        glds16(gb_ + 16 * K, lb_ + 512);                                    \
    }

    int NT = K >> 5;                 // K=1024 -> 32 tiles
    STAGE3_(0, 0);
    STAGE3_(1, 1);
    asm volatile("s_waitcnt vmcnt(4)" ::: "memory");   // tile 0 resident
    __builtin_amdgcn_s_barrier();

    const uint16_t* Ab = &As[0][0][0];
    const uint16_t* Bb = &Bs[0][0][0];
    int s = (quad ^ (l16 & 3)) * 8;  // swizzled read slot (loop-invariant)
    int bc = 0, bs = 2;
    for (int t = 0; t < NT; ++t) {
        if (t + 2 < NT) STAGE3_(bs, t + 2);
        __builtin_amdgcn_sched_barrier(0);   // pin stage issue before compute
        const uint16_t* Ac = Ab + bc * 4096;
        const uint16_t* Bc = Bb + bc * 4096;
        short8 af[4], bfr[4];
        #pragma unroll
        for (int i = 0; i < 4; i++)
            af[i] = *(const short8*)&Ac[(wr + i * 16 + l16) * 32 + s];
        #pragma unroll
        for (int j = 0; j < 4; j++)
            bfr[j] = *(const short8*)&Bc[(wc + j * 16 + l16) * 32 + s];
        #pragma unroll
        for (int i = 0; i < 4; i++)
            #pragma unroll
            for (int j = 0; j < 4; j++)
                acc[i][j] = __builtin_amdgcn_mfma_f32_16x16x32_bf16(
                    af[i], bfr[j], acc[i][j], 0, 0, 0);
        if (t + 2 < NT) {
            asm volatile("s_waitcnt vmcnt(4)" ::: "memory");  // t+1 resident
        } else {
            asm volatile("s_waitcnt vmcnt(0)" ::: "memory");  // tail drain
        }
        __builtin_amdgcn_s_barrier();
        bc = (bc == 2) ? 0 : bc + 1;
        bs = (bs == 2) ? 0 : bs + 1;
    }
#undef STAGE3_

    #pragma unroll
    for (int i = 0; i < 4; i++) {
        #pragma unroll
        for (int j = 0; j < 4; j++) {
            int rbase = row0 + wr + i * 16 + quad * 4;
            int cg = col0 + wc + j * 16 + l16;
            #pragma unroll
            for (int r = 0; r < 4; r++) {
                if (OUT_F32)
                    ((float*)Cv)[(size_t)(rbase + r) * N + cg] = acc[i][j][r];
                else
                    ((uint16_t*)Cv)[(size_t)(rbase + r) * N + cg] = f2b(acc[i][j][r]);
            }
        }
    }
}

// ---------------- MFMA flash attention with sink ---------------------------
// WAVE-BALANCED: block (pair,bh) covers strips hi=31-pair and lo=pair.
// Each of the 4 waves owns ONE 16-row tile of hi (qt=0, rows hi*64+w*16)
// and ONE 16-row tile of lo (qt=1, rows lo*64+w*16): every wave computes
// exactly (hi+1)+(lo+1) = 33 qt-units -- no intra-block wave imbalance at
// the per-ktile barrier (previously heavy waves did up to 64 while light
// waves idled; SIMDs 2,3 mostly idle). 1D grid id = pair*32+bh so
// id%8 = bh%8 -> same-bh blocks share one XCD L2. Double-buffered K/V LDS,
// 1 barrier/ktile, register prefetch. S^T = K*Q^T; P via per-wave LDS;
// O += P*V.
__global__ __launch_bounds__(256, 2)
void attn_mfma(const uint16_t* __restrict__ qkv,
               const float* __restrict__ sink,
               uint16_t* __restrict__ y) {
    __shared__ uint16_t Ks[2][64][72];   // [buf][key][d]   18432 B
    __shared__ uint16_t Vt[2][64][72];   // [buf][d][key]   18432 B (swizzled)
    __shared__ uint16_t Pl[4][32][72];   // per-wave [q][key] 18432 B

    int tid = threadIdx.x;
    int w = tid >> 6, lane = tid & 63;
    int quad = lane >> 4, l16 = lane & 15;

    int id = blockIdx.x;
    int pair = id >> 5, bh = id & 31;
    int b = bh >> 4, h = bh & 15;
    int hi = 31 - pair, lo = pair;
    int q0s[2];
    q0s[0] = hi * 64 + w * 16;          // heavy-strip 16-row tile
    q0s[1] = lo * 64 + w * 16;          // light-strip 16-row tile
    int ktiles = hi + 1;                // tiles staged & iterated by block
    int myk1 = lo + 1;                  // iterations where qt=1 is active

    const uint16_t* qkv_b = qkv + (size_t)b * T_ * 3072;

    // ---- Q fragments: 2 qt x 2 kd, pre-scaled by 1/8 (exact) ----
    short8 qf[2][2];
    #pragma unroll
    for (int qt = 0; qt < 2; qt++) {
        int qrow = q0s[qt] + l16;
        #pragma unroll
        for (int kd = 0; kd < 2; kd++) {
            uint4 raw = *(const uint4*)(qkv_b + (size_t)qrow * 3072 + h * 64 +
                                        kd * 32 + quad * 8);
            const uint16_t* rp = (const uint16_t*)&raw;
            short8 f;
            #pragma unroll
            for (int j = 0; j < 8; j++)
                f[j] = (short)f2b(bf2f(rp[j]) * 0.125f);
            qf[qt][kd] = f;
        }
    }

    float m_s[2], l_s[2];
    m_s[0] = m_s[1] = sink[h];
    l_s[0] = l_s[1] = 1.0f;
    floatx4 acc_o[2][4];
    #pragma unroll
    for (int qt = 0; qt < 2; qt++)
        #pragma unroll
        for (int dt = 0; dt < 4; dt++)
            acc_o[qt][dt] = (floatx4){0.f, 0.f, 0.f, 0.f};

    // ---- staging map: thread (t2,dg): key rows 2t2,2t2+1, dims dg*8..+7 ----
    int t2 = tid >> 3;
    int dg = tid & 7;
    const uint16_t* kgp = qkv_b + 1024 + h * 64 + (size_t)(2 * t2) * 3072 + dg * 8;
    const uint16_t* vgp = kgp + 1024;
    int vcw = 2 * (t2 ^ (4 * dg));   // swizzled u16 col for V^T key-pair store

    uint4 kr0 = *(const uint4*)(kgp);
    uint4 kr1 = *(const uint4*)(kgp + 3072);
    uint4 vr0 = *(const uint4*)(vgp);
    uint4 vr1 = *(const uint4*)(vgp + 3072);
    // store tile 0 -> buf 0
    {
        *(uint4*)&Ks[0][2 * t2][dg * 8] = kr0;
        *(uint4*)&Ks[0][2 * t2 + 1][dg * 8] = kr1;
        const uint16_t* a0 = (const uint16_t*)&vr0;
        const uint16_t* a1 = (const uint16_t*)&vr1;
        #pragma unroll
        for (int j = 0; j < 8; j++)
            *(uint32_t*)&Vt[0][dg * 8 + j][vcw] =
                (uint32_t)a0[j] | ((uint32_t)a1[j] << 16);
    }
    if (ktiles > 1) {   // preload tile 1
        kr0 = *(const uint4*)(kgp + 64 * 3072);
        kr1 = *(const uint4*)(kgp + 64 * 3072 + 3072);
        vr0 = *(const uint4*)(vgp + 64 * 3072);
        vr1 = *(const uint4*)(vgp + 64 * 3072 + 3072);
    }
    __syncthreads();

    for (int kt = 0; kt < ktiles; kt++) {
        int cur = kt & 1;
        // ---- store prefetched tile kt+1 into the other buffer ----
        if (kt + 1 < ktiles) {
            *(uint4*)&Ks[cur ^ 1][2 * t2][dg * 8] = kr0;
            *(uint4*)&Ks[cur ^ 1][2 * t2 + 1][dg * 8] = kr1;
            const uint16_t* a0 = (const uint16_t*)&vr0;
            const uint16_t* a1 = (const uint16_t*)&vr1;
            #pragma unroll
            for (int j = 0; j < 8; j++)
                *(uint32_t*)&Vt[cur ^ 1][dg * 8 + j][vcw] =
                    (uint32_t)a0[j] | ((uint32_t)a1[j] << 16);
        }
        // ---- issue prefetch of tile kt+2 (lands during this iter) ----
        if (kt + 2 < ktiles) {
            size_t off = (size_t)(kt + 2) * 64 * 3072;
            kr0 = *(const uint4*)(kgp + off);
            kr1 = *(const uint4*)(kgp + off + 3072);
            vr0 = *(const uint4*)(vgp + off);
            vr1 = *(const uint4*)(vgp + off + 3072);
        }
        // ---- K and V fragments (shared by both qt; all waves active) ----
        short8 kf[4][2];
        #pragma unroll
        for (int rt = 0; rt < 4; rt++) {
            kf[rt][0] = *(const short8*)&Ks[cur][rt * 16 + l16][quad * 8];
            kf[rt][1] = *(const short8*)&Ks[cur][rt * 16 + l16][32 + quad * 8];
        }
        short8 vf[2][4];
        #pragma unroll
        for (int kb = 0; kb < 2; kb++)
            #pragma unroll
            for (int dt = 0; dt < 4; dt++) {
                int d = dt * 16 + l16;
                int col = 2 * (((kb * 16) + quad * 4) ^ (4 * (d >> 3)));
                vf[kb][dt] = *(const short8*)&Vt[cur][d][col];
            }
        #pragma unroll
        for (int qt = 0; qt < 2; qt++) {
            if (qt == 1 && kt >= myk1) continue;   // light tile done (uniform)
            // ---- S^T = K * Q^T : key = rt*16+quad*4+r, q = l16 ----
            floatx4 acc_s[4];
            #pragma unroll
            for (int rt = 0; rt < 4; rt++)
                acc_s[rt] = (floatx4){0.f, 0.f, 0.f, 0.f};
            #pragma unroll
            for (int rt = 0; rt < 4; rt++) {
                acc_s[rt] = __builtin_amdgcn_mfma_f32_16x16x32_bf16(
                    kf[rt][0], qf[qt][0], acc_s[rt], 0, 0, 0);
                acc_s[rt] = __builtin_amdgcn_mfma_f32_16x16x32_bf16(
                    kf[rt][1], qf[qt][1], acc_s[rt], 0, 0, 0);
            }
            // ---- causal mask: only this qt's diagonal tile ----
            int dqt = (qt == 0) ? hi : lo;
            if (kt == dqt) {
                int qg = q0s[qt] + l16;
                #pragma unroll
                for (int rt = 0; rt < 4; rt++) {
                    int kg = kt * 64 + rt * 16 + quad * 4;
                    #pragma unroll
                    for (int r = 0; r < 4; r++)
                        if (kg + r > qg) acc_s[rt][r] = -1e30f;
                }
            }
            // ---- online softmax (q = l16; reduce across quads) ----
            float mx = -1e30f;
            #pragma unroll
            for (int rt = 0; rt < 4; rt++)
                #pragma unroll
                for (int r = 0; r < 4; r++) mx = fmaxf(mx, acc_s[rt][r]);
            mx = fmaxf(mx, __shfl_xor(mx, 16));
            mx = fmaxf(mx, __shfl_xor(mx, 32));
            float mnew = fmaxf(m_s[qt], mx);
            float alpha = __expf(m_s[qt] - mnew);
            m_s[qt] = mnew;
            float psum = 0.f;
            #pragma unroll
            for (int rt = 0; rt < 4; rt++) {
                float p0 = __expf(acc_s[rt][0] - mnew);
                float p1 = __expf(acc_s[rt][1] - mnew);
                float p2 = __expf(acc_s[rt][2] - mnew);
                float p3 = __expf(acc_s[rt][3] - mnew);
                psum += (p0 + p1) + (p2 + p3);
                uint2 pk;
                pk.x = (uint32_t)f2b(p0) | ((uint32_t)f2b(p1) << 16);
                pk.y = (uint32_t)f2b(p2) | ((uint32_t)f2b(p3) << 16);
                *(uint2*)&Pl[w][qt * 16 + l16][rt * 16 + quad * 4] = pk;
            }
            psum += __shfl_xor(psum, 16);
            psum += __shfl_xor(psum, 32);
            l_s[qt] = l_s[qt] * alpha + psum;
            #pragma unroll
            for (int r = 0; r < 4; r++) {
                float ar = __shfl(alpha, (lane & 48) | (quad * 4 + r));
                #pragma unroll
                for (int dt = 0; dt < 4; dt++) acc_o[qt][dt][r] *= ar;
            }
            // ---- O += P * V ----
            #pragma unroll
            for (int kb = 0; kb < 2; kb++) {
                short8 pf = *(const short8*)&Pl[w][qt * 16 + l16][kb * 32 + quad * 8];
                #pragma unroll
                for (int dt = 0; dt < 4; dt++)
                    acc_o[qt][dt] = __builtin_amdgcn_mfma_f32_16x16x32_bf16(
                        pf, vf[kb][dt], acc_o[qt][dt], 0, 0, 0);
            }
        }
        __syncthreads();
    }

    // ---- epilogue: normalize by l (per-q via in-quad shuffle), store bf16 --
    #pragma unroll
    for (int qt = 0; qt < 2; qt++) {
        #pragma unroll
        for (int r = 0; r < 4; r++) {
            float lr = __shfl(l_s[qt], (lane & 48) | (quad * 4 + r));
            float inv = 1.0f / lr;
            int qg = q0s[qt] + quad * 4 + r;
            uint16_t* yp = y + (size_t)(b * T_ + qg) * 1024 + h * 64;
            #pragma unroll
            for (int dt = 0; dt < 4; dt++)
                yp[dt * 16 + l16] = f2b(acc_o[qt][dt][r] * inv);
        }
    }
}

extern "C" void kernel_launch(void* const* d_in, const int* in_sizes, int n_in,
                              void* d_out, int out_size, void* d_ws, size_t ws_size,
                              hipStream_t stream) {
    const float* x      = (const float*)d_in[0];  // [B,T,C] fp32
    const float* w_qkv  = (const float*)d_in[1];  // [C, 3HD] fp32
    const float* w_proj = (const float*)d_in[2];  // [HD, C] fp32
    const float* sink   = (const float*)d_in[3];  // [H] fp32
    float* out          = (float*)d_out;          // [B,T,C] fp32

    char* ws = (char*)d_ws;
    uint16_t* wt_qkv  = (uint16_t*)ws;                       // [3072,1024] 6.29 MB
    uint16_t* wt_proj = (uint16_t*)(ws + 6291456);           // [1024,1024] 2.10 MB
    uint16_t* x_c     = (uint16_t*)(ws + 8388608);           // [4096,1024] 8.39 MB
    uint16_t* qkv     = (uint16_t*)(ws + 16777216);          // [4096,3072] 25.17 MB
    uint16_t* yb      = (uint16_t*)(ws + 41943040);          // [4096,1024] 8.39 MB

    canon_x<<<4194304 / 1024, 256, 0, stream>>>(x, x_c, 4194304);
    transpose_conv<<<dim3(3072 / 32, 1024 / 32), dim3(32, 8), 0, stream>>>(
        w_qkv, wt_qkv, 1024, 3072);
    transpose_conv<<<dim3(1024 / 32, 1024 / 32), dim3(32, 8), 0, stream>>>(
        w_proj, wt_proj, 1024, 1024);

    // 1D grids, nwg % 8 == 0 (bijective XCD swizzle inside)
    gemm_bt<false><<<dim3(768), 256, 0, stream>>>(
        x_c, wt_qkv, qkv, 4096, 3072, 1024);

    // pair-balanced grid: id = pair*32 + bh  (id%8 == bh%8 -> XCD locality)
    attn_mfma<<<dim3(16 * 32), 256, 0, stream>>>(qkv, sink, yb);

    gemm_bt<true><<<dim3(256), 256, 0, stream>>>(
        yb, wt_proj, out, 4096, 1024, 1024);
}

// Round 5
// 181.144 us; speedup vs baseline: 1.1047x; 1.0328x over previous
//
#include <hip/hip_runtime.h>
#include <hip/hip_bf16.h>
#include <stdint.h>

#define B_ 2
#define T_ 2048
#define C_ 1024
#define H_ 16
#define D_ 64

typedef __attribute__((ext_vector_type(8))) short short8;
typedef __attribute__((ext_vector_type(4))) float floatx4;

__device__ __forceinline__ float bf2f(uint16_t b) {
    return __uint_as_float(((uint32_t)b) << 16);
}
__device__ __forceinline__ uint16_t f2b(float f) {
    __hip_bfloat16 h = __float2bfloat16(f);  // RNE
    return *(uint16_t*)&h;
}
// 2^x via v_exp_f32 (gfx9 transcendentals are HW-interlocked; reg-only asm)
__device__ __forceinline__ float exp2v(float x) {
    float r;
    asm("v_exp_f32 %0, %1" : "=v"(r) : "v"(x));
    return r;
}
// pack 2 f32 -> 2 bf16 (RNE), lo first
__device__ __forceinline__ uint32_t cvtpk(float lo, float hi) {
    uint32_t r;
    asm("v_cvt_pk_bf16_f32 %0, %1, %2" : "=v"(r) : "v"(lo), "v"(hi));
    return r;
}
__device__ __forceinline__ void glds16(const uint16_t* g, uint16_t* l) {
    __builtin_amdgcn_global_load_lds(
        (const __attribute__((address_space(1))) uint32_t*)g,
        (__attribute__((address_space(3))) uint32_t*)l, 16, 0, 0);
}

// ---- fused prep: canon x (fp32->bf16) + both weight transposes ------------
// blocks [0,4096): canon; [4096,7168): w_qkv transpose; [7168,8192): w_proj.
__global__ void prep(const float* __restrict__ x, uint16_t* __restrict__ x_c,
                     const float* __restrict__ w_qkv, uint16_t* __restrict__ wt_qkv,
                     const float* __restrict__ w_proj, uint16_t* __restrict__ wt_proj) {
    __shared__ uint16_t tile[32][33];
    int id = blockIdx.x;
    int tid = threadIdx.x;
    if (id < 4096) {
        int i = (id * 256 + tid) * 4;
        float4 v = *(const float4*)(x + i);
        x_c[i + 0] = f2b(v.x);
        x_c[i + 1] = f2b(v.y);
        x_c[i + 2] = f2b(v.z);
        x_c[i + 3] = f2b(v.w);
        return;
    }
    const float* in;
    uint16_t* out;
    int R, W, bx, by;
    if (id < 7168) {
        int tb = id - 4096;
        in = w_qkv; out = wt_qkv; R = 1024; W = 3072;
        bx = tb % 96; by = tb / 96;
    } else {
        int tb = id - 7168;
        in = w_proj; out = wt_proj; R = 1024; W = 1024;
        bx = tb & 31; by = tb >> 5;
    }
    int tx = tid & 31, ty = tid >> 5;
    int c0 = bx * 32, r0 = by * 32;
    #pragma unroll
    for (int i = 0; i < 32; i += 8)
        tile[ty + i][tx] = f2b(in[(size_t)(r0 + ty + i) * W + (c0 + tx)]);
    __syncthreads();
    #pragma unroll
    for (int i = 0; i < 32; i += 8)
        out[(size_t)(c0 + ty + i) * R + (r0 + tx)] = tile[tx][ty + i];
}

// ------- GEMM: C[M,N] = A[M,K] @ Bt[N,K]^T ; bf16 in, fp32 acc -------------
// Counted-vmcnt pipeline (T3+T4): BK=32, THREE LDS buffers (48 KB -> 3
// blocks/CU), depth-2 global_load_lds prefetch. Never drain vmcnt to 0 in
// the main loop (m218). XOR slot swizzle with pre-swizzled global source.
// Grid 1D, bijective XCD swizzle (nwg % 8 == 0), A-panel-major.
template <bool OUT_F32>
__global__ __launch_bounds__(256, 3)
void gemm_bt(const uint16_t* __restrict__ A, const uint16_t* __restrict__ Bt,
             void* __restrict__ Cv, int M, int N, int K) {
    __shared__ uint16_t As[3][128][32];   // 24 KB
    __shared__ uint16_t Bs[3][128][32];   // 24 KB
    int tid = threadIdx.x;
    int w = tid >> 6, lane = tid & 63;
    int quad = lane >> 4, l16 = lane & 15;
    int wr = (w >> 1) * 64, wc = (w & 1) * 64;

    int nwg = gridDim.x;
    int wg = (blockIdx.x & 7) * (nwg >> 3) + (blockIdx.x >> 3);
    int nby = N >> 7;
    int row0 = (wg / nby) * 128;
    int col0 = (wg % nby) * 128;

    int sr = w * 32 + (lane >> 2);
    int gsc = ((lane & 3) ^ ((lane >> 2) & 3)) * 8;
    uint16_t* lA0 = &As[0][sr][(lane & 3) * 8];
    uint16_t* lB0 = &Bs[0][sr][(lane & 3) * 8];
    const uint16_t* gA = A + (size_t)(row0 + sr) * K + gsc;
    const uint16_t* gB = Bt + (size_t)(col0 + sr) * K + gsc;

    floatx4 acc[4][4];
    #pragma unroll
    for (int i = 0; i < 4; i++)
        #pragma unroll
        for (int j = 0; j < 4; j++)
            acc[i][j] = (floatx4){0.f, 0.f, 0.f, 0.f};

#define STAGE3_(bs_, t_)                                                    \
    {                                                                       \
        const uint16_t* ga_ = gA + (size_t)(t_) * 32;                       \
        const uint16_t* gb_ = gB + (size_t)(t_) * 32;                       \
        uint16_t* la_ = lA0 + (bs_) * 4096;                                 \
        uint16_t* lb_ = lB0 + (bs_) * 4096;                                 \
        glds16(ga_, la_);                                                   \
        glds16(ga_ + 16 * K, la_ + 512);                                    \
        glds16(gb_, lb_);                                                   \
        glds16(gb_ + 16 * K, lb_ + 512);                                    \
    }

    int NT = K >> 5;                 // K=1024 -> 32 tiles
    STAGE3_(0, 0);
    STAGE3_(1, 1);
    asm volatile("s_waitcnt vmcnt(4)" ::: "memory");   // tile 0 resident
    __builtin_amdgcn_s_barrier();

    const uint16_t* Ab = &As[0][0][0];
    const uint16_t* Bb = &Bs[0][0][0];
    int s = (quad ^ (l16 & 3)) * 8;  // swizzled read slot (loop-invariant)
    int bc = 0, bs = 2;
    for (int t = 0; t < NT; ++t) {
        if (t + 2 < NT) STAGE3_(bs, t + 2);
        __builtin_amdgcn_sched_barrier(0);   // pin stage issue before compute
        const uint16_t* Ac = Ab + bc * 4096;
        const uint16_t* Bc = Bb + bc * 4096;
        short8 af[4], bfr[4];
        #pragma unroll
        for (int i = 0; i < 4; i++)
            af[i] = *(const short8*)&Ac[(wr + i * 16 + l16) * 32 + s];
        #pragma unroll
        for (int j = 0; j < 4; j++)
            bfr[j] = *(const short8*)&Bc[(wc + j * 16 + l16) * 32 + s];
        #pragma unroll
        for (int i = 0; i < 4; i++)
            #pragma unroll
            for (int j = 0; j < 4; j++)
                acc[i][j] = __builtin_amdgcn_mfma_f32_16x16x32_bf16(
                    af[i], bfr[j], acc[i][j], 0, 0, 0);
        if (t + 2 < NT) {
            asm volatile("s_waitcnt vmcnt(4)" ::: "memory");  // t+1 resident
        } else {
            asm volatile("s_waitcnt vmcnt(0)" ::: "memory");  // tail drain
        }
        __builtin_amdgcn_s_barrier();
        bc = (bc == 2) ? 0 : bc + 1;
        bs = (bs == 2) ? 0 : bs + 1;
    }
#undef STAGE3_

    #pragma unroll
    for (int i = 0; i < 4; i++) {
        #pragma unroll
        for (int j = 0; j < 4; j++) {
            int rbase = row0 + wr + i * 16 + quad * 4;
            int cg = col0 + wc + j * 16 + l16;
            #pragma unroll
            for (int r = 0; r < 4; r++) {
                if (OUT_F32)
                    ((float*)Cv)[(size_t)(rbase + r) * N + cg] = acc[i][j][r];
                else
                    ((uint16_t*)Cv)[(size_t)(rbase + r) * N + cg] = f2b(acc[i][j][r]);
            }
        }
    }
}

// ---------------- MFMA flash attention with sink ---------------------------
// WAVE-BALANCED (round 3) + log2-space softmax: Q pre-scaled by
// 0.125*log2(e) and sink by log2(e), so P = 2^(S'-m') via bare v_exp_f32.
// Defer-max (T13, THR=8): skip the O-rescale (4 bpermute + 16 mul + exp)
// whenever the tile max doesn't exceed running max by >8 (log2 units);
// P then bounded by 2^8 -- safe in bf16/f32. P->bf16 packing via
// v_cvt_pk_bf16_f32 (2 f32 -> 1 packed word, replaces f2b+or+shl).
__global__ __launch_bounds__(256, 2)
void attn_mfma(const uint16_t* __restrict__ qkv,
               const float* __restrict__ sink,
               uint16_t* __restrict__ y) {
    __shared__ uint16_t Ks[2][64][72];   // [buf][key][d]   18432 B
    __shared__ uint16_t Vt[2][64][72];   // [buf][d][key]   18432 B (swizzled)
    __shared__ uint16_t Pl[4][32][72];   // per-wave [q][key] 18432 B

    int tid = threadIdx.x;
    int w = tid >> 6, lane = tid & 63;
    int quad = lane >> 4, l16 = lane & 15;

    int id = blockIdx.x;
    int pair = id >> 5, bh = id & 31;
    int b = bh >> 4, h = bh & 15;
    int hi = 31 - pair, lo = pair;
    int q0s[2];
    q0s[0] = hi * 64 + w * 16;          // heavy-strip 16-row tile
    q0s[1] = lo * 64 + w * 16;          // light-strip 16-row tile
    int ktiles = hi + 1;                // tiles staged & iterated by block
    int myk1 = lo + 1;                  // iterations where qt=1 is active

    const uint16_t* qkv_b = qkv + (size_t)b * T_ * 3072;

    // ---- Q fragments: 2 qt x 2 kd, pre-scaled by log2(e)/8 ----
    const float QSC = 0.125f * 1.44269504f;
    short8 qf[2][2];
    #pragma unroll
    for (int qt = 0; qt < 2; qt++) {
        int qrow = q0s[qt] + l16;
        #pragma unroll
        for (int kd = 0; kd < 2; kd++) {
            uint4 raw = *(const uint4*)(qkv_b + (size_t)qrow * 3072 + h * 64 +
                                        kd * 32 + quad * 8);
            const uint16_t* rp = (const uint16_t*)&raw;
            short8 f;
            #pragma unroll
            for (int j = 0; j < 8; j++)
                f[j] = (short)f2b(bf2f(rp[j]) * QSC);
            qf[qt][kd] = f;
        }
    }

    float m_s[2], l_s[2];
    m_s[0] = m_s[1] = sink[h] * 1.44269504f;   // log2 space
    l_s[0] = l_s[1] = 1.0f;
    floatx4 acc_o[2][4];
    #pragma unroll
    for (int qt = 0; qt < 2; qt++)
        #pragma unroll
        for (int dt = 0; dt < 4; dt++)
            acc_o[qt][dt] = (floatx4){0.f, 0.f, 0.f, 0.f};

    // ---- staging map: thread (t2,dg): key rows 2t2,2t2+1, dims dg*8..+7 ----
    int t2 = tid >> 3;
    int dg = tid & 7;
    const uint16_t* kgp = qkv_b + 1024 + h * 64 + (size_t)(2 * t2) * 3072 + dg * 8;
    const uint16_t* vgp = kgp + 1024;
    int vcw = 2 * (t2 ^ (4 * dg));   // swizzled u16 col for V^T key-pair store

    uint4 kr0 = *(const uint4*)(kgp);
    uint4 kr1 = *(const uint4*)(kgp + 3072);
    uint4 vr0 = *(const uint4*)(vgp);
    uint4 vr1 = *(const uint4*)(vgp + 3072);
    // store tile 0 -> buf 0
    {
        *(uint4*)&Ks[0][2 * t2][dg * 8] = kr0;
        *(uint4*)&Ks[0][2 * t2 + 1][dg * 8] = kr1;
        const uint16_t* a0 = (const uint16_t*)&vr0;
        const uint16_t* a1 = (const uint16_t*)&vr1;
        #pragma unroll
        for (int j = 0; j < 8; j++)
            *(uint32_t*)&Vt[0][dg * 8 + j][vcw] =
                (uint32_t)a0[j] | ((uint32_t)a1[j] << 16);
    }
    if (ktiles > 1) {   // preload tile 1
        kr0 = *(const uint4*)(kgp + 64 * 3072);
        kr1 = *(const uint4*)(kgp + 64 * 3072 + 3072);
        vr0 = *(const uint4*)(vgp + 64 * 3072);
        vr1 = *(const uint4*)(vgp + 64 * 3072 + 3072);
    }
    __syncthreads();

    for (int kt = 0; kt < ktiles; kt++) {
        int cur = kt & 1;
        // ---- store prefetched tile kt+1 into the other buffer ----
        if (kt + 1 < ktiles) {
            *(uint4*)&Ks[cur ^ 1][2 * t2][dg * 8] = kr0;
            *(uint4*)&Ks[cur ^ 1][2 * t2 + 1][dg * 8] = kr1;
            const uint16_t* a0 = (const uint16_t*)&vr0;
            const uint16_t* a1 = (const uint16_t*)&vr1;
            #pragma unroll
            for (int j = 0; j < 8; j++)
                *(uint32_t*)&Vt[cur ^ 1][dg * 8 + j][vcw] =
                    (uint32_t)a0[j] | ((uint32_t)a1[j] << 16);
        }
        // ---- issue prefetch of tile kt+2 (lands during this iter) ----
        if (kt + 2 < ktiles) {
            size_t off = (size_t)(kt + 2) * 64 * 3072;
            kr0 = *(const uint4*)(kgp + off);
            kr1 = *(const uint4*)(kgp + off + 3072);
            vr0 = *(const uint4*)(vgp + off);
            vr1 = *(const uint4*)(vgp + off + 3072);
        }
        // ---- K and V fragments (shared by both qt; all waves active) ----
        short8 kf[4][2];
        #pragma unroll
        for (int rt = 0; rt < 4; rt++) {
            kf[rt][0] = *(const short8*)&Ks[cur][rt * 16 + l16][quad * 8];
            kf[rt][1] = *(const short8*)&Ks[cur][rt * 16 + l16][32 + quad * 8];
        }
        short8 vf[2][4];
        #pragma unroll
        for (int kb = 0; kb < 2; kb++)
            #pragma unroll
            for (int dt = 0; dt < 4; dt++) {
                int d = dt * 16 + l16;
                int col = 2 * (((kb * 16) + quad * 4) ^ (4 * (d >> 3)));
                vf[kb][dt] = *(const short8*)&Vt[cur][d][col];
            }
        #pragma unroll
        for (int qt = 0; qt < 2; qt++) {
            if (qt == 1 && kt >= myk1) continue;   // light tile done (uniform)
            // ---- S^T = K * Q^T : key = rt*16+quad*4+r, q = l16 ----
            floatx4 acc_s[4];
            #pragma unroll
            for (int rt = 0; rt < 4; rt++)
                acc_s[rt] = (floatx4){0.f, 0.f, 0.f, 0.f};
            #pragma unroll
            for (int rt = 0; rt < 4; rt++) {
                acc_s[rt] = __builtin_amdgcn_mfma_f32_16x16x32_bf16(
                    kf[rt][0], qf[qt][0], acc_s[rt], 0, 0, 0);
                acc_s[rt] = __builtin_amdgcn_mfma_f32_16x16x32_bf16(
                    kf[rt][1], qf[qt][1], acc_s[rt], 0, 0, 0);
            }
            // ---- causal mask: only this qt's diagonal tile ----
            int dqt = (qt == 0) ? hi : lo;
            if (kt == dqt) {
                int qg = q0s[qt] + l16;
                #pragma unroll
                for (int rt = 0; rt < 4; rt++) {
                    int kg = kt * 64 + rt * 16 + quad * 4;
                    #pragma unroll
                    for (int r = 0; r < 4; r++)
                        if (kg + r > qg) acc_s[rt][r] = -1e30f;
                }
            }
            // ---- online softmax in log2 space (q = l16) ----
            float mx = -1e30f;
            #pragma unroll
            for (int rt = 0; rt < 4; rt++)
                #pragma unroll
                for (int r = 0; r < 4; r++) mx = fmaxf(mx, acc_s[rt][r]);
            mx = fmaxf(mx, __shfl_xor(mx, 16));
            mx = fmaxf(mx, __shfl_xor(mx, 32));
            float mold = m_s[qt];
            // T13 defer-max: only rescale when tile max exceeds m by >8
            if (!__all(mx <= mold + 8.0f)) {
                float mnew = fmaxf(mold, mx);
                float alpha = exp2v(mold - mnew);
                m_s[qt] = mnew;
                l_s[qt] *= alpha;
                #pragma unroll
                for (int r = 0; r < 4; r++) {
                    float ar = __shfl(alpha, (lane & 48) | (quad * 4 + r));
                    #pragma unroll
                    for (int dt = 0; dt < 4; dt++) acc_o[qt][dt][r] *= ar;
                }
            }
            float mcur = m_s[qt];
            float psum = 0.f;
            #pragma unroll
            for (int rt = 0; rt < 4; rt++) {
                float p0 = exp2v(acc_s[rt][0] - mcur);
                float p1 = exp2v(acc_s[rt][1] - mcur);
                float p2 = exp2v(acc_s[rt][2] - mcur);
                float p3 = exp2v(acc_s[rt][3] - mcur);
                psum += (p0 + p1) + (p2 + p3);
                uint2 pk;
                pk.x = cvtpk(p0, p1);
                pk.y = cvtpk(p2, p3);
                *(uint2*)&Pl[w][qt * 16 + l16][rt * 16 + quad * 4] = pk;
            }
            psum += __shfl_xor(psum, 16);
            psum += __shfl_xor(psum, 32);
            l_s[qt] += psum;
            // ---- O += P * V ----
            #pragma unroll
            for (int kb = 0; kb < 2; kb++) {
                short8 pf = *(const short8*)&Pl[w][qt * 16 + l16][kb * 32 + quad * 8];
                #pragma unroll
                for (int dt = 0; dt < 4; dt++)
                    acc_o[qt][dt] = __builtin_amdgcn_mfma_f32_16x16x32_bf16(
                        pf, vf[kb][dt], acc_o[qt][dt], 0, 0, 0);
            }
        }
        __syncthreads();
    }

    // ---- epilogue: normalize by l (per-q via in-quad shuffle), store bf16 --
    #pragma unroll
    for (int qt = 0; qt < 2; qt++) {
        #pragma unroll
        for (int r = 0; r < 4; r++) {
            float lr = __shfl(l_s[qt], (lane & 48) | (quad * 4 + r));
            float inv = 1.0f / lr;
            int qg = q0s[qt] + quad * 4 + r;
            uint16_t* yp = y + (size_t)(b * T_ + qg) * 1024 + h * 64;
            #pragma unroll
            for (int dt = 0; dt < 4; dt++)
                yp[dt * 16 + l16] = f2b(acc_o[qt][dt][r] * inv);
        }
    }
}

extern "C" void kernel_launch(void* const* d_in, const int* in_sizes, int n_in,
                              void* d_out, int out_size, void* d_ws, size_t ws_size,
                              hipStream_t stream) {
    const float* x      = (const float*)d_in[0];  // [B,T,C] fp32
    const float* w_qkv  = (const float*)d_in[1];  // [C, 3HD] fp32
    const float* w_proj = (const float*)d_in[2];  // [HD, C] fp32
    const float* sink   = (const float*)d_in[3];  // [H] fp32
    float* out          = (float*)d_out;          // [B,T,C] fp32

    char* ws = (char*)d_ws;
    uint16_t* wt_qkv  = (uint16_t*)ws;                       // [3072,1024] 6.29 MB
    uint16_t* wt_proj = (uint16_t*)(ws + 6291456);           // [1024,1024] 2.10 MB
    uint16_t* x_c     = (uint16_t*)(ws + 8388608);           // [4096,1024] 8.39 MB
    uint16_t* qkv     = (uint16_t*)(ws + 16777216);          // [4096,3072] 25.17 MB
    uint16_t* yb      = (uint16_t*)(ws + 41943040);          // [4096,1024] 8.39 MB

    // fused prep: canon + both transposes in ONE dispatch
    prep<<<dim3(8192), 256, 0, stream>>>(x, x_c, w_qkv, wt_qkv, w_proj, wt_proj);

    // 1D grids, nwg % 8 == 0 (bijective XCD swizzle inside)
    gemm_bt<false><<<dim3(768), 256, 0, stream>>>(
        x_c, wt_qkv, qkv, 4096, 3072, 1024);

    // pair-balanced grid: id = pair*32 + bh  (id%8 == bh%8 -> XCD locality)
    attn_mfma<<<dim3(16 * 32), 256, 0, stream>>>(qkv, sink, yb);

    gemm_bt<true><<<dim3(256), 256, 0, stream>>>(
        yb, wt_proj, out, 4096, 1024, 1024);
}

// Round 6
// 177.012 us; speedup vs baseline: 1.1305x; 1.0233x over previous
//
#include <hip/hip_runtime.h>
#include <hip/hip_bf16.h>
#include <stdint.h>

#define B_ 2
#define T_ 2048
#define C_ 1024
#define H_ 16
#define D_ 64

typedef __attribute__((ext_vector_type(8))) short short8;
typedef __attribute__((ext_vector_type(4))) float floatx4;

__device__ __forceinline__ float bf2f(uint16_t b) {
    return __uint_as_float(((uint32_t)b) << 16);
}
__device__ __forceinline__ uint16_t f2b(float f) {
    __hip_bfloat16 h = __float2bfloat16(f);  // RNE
    return *(uint16_t*)&h;
}
// 2^x via v_exp_f32 (gfx9 transcendentals are HW-interlocked; reg-only asm)
__device__ __forceinline__ float exp2v(float x) {
    float r;
    asm("v_exp_f32 %0, %1" : "=v"(r) : "v"(x));
    return r;
}
// pack 2 f32 -> 2 bf16 (RNE), lo first
__device__ __forceinline__ uint32_t cvtpk(float lo, float hi) {
    uint32_t r;
    asm("v_cvt_pk_bf16_f32 %0, %1, %2" : "=v"(r) : "v"(lo), "v"(hi));
    return r;
}
__device__ __forceinline__ void glds16(const uint16_t* g, uint16_t* l) {
    __builtin_amdgcn_global_load_lds(
        (const __attribute__((address_space(1))) uint32_t*)g,
        (__attribute__((address_space(3))) uint32_t*)l, 16, 0, 0);
}

// ---- fused prep: canon x (fp32->bf16) + both weight transposes ------------
// blocks [0,4096): canon; [4096,7168): w_qkv transpose; [7168,8192): w_proj.
__global__ void prep(const float* __restrict__ x, uint16_t* __restrict__ x_c,
                     const float* __restrict__ w_qkv, uint16_t* __restrict__ wt_qkv,
                     const float* __restrict__ w_proj, uint16_t* __restrict__ wt_proj) {
    __shared__ uint16_t tile[32][33];
    int id = blockIdx.x;
    int tid = threadIdx.x;
    if (id < 4096) {
        int i = (id * 256 + tid) * 4;
        float4 v = *(const float4*)(x + i);
        x_c[i + 0] = f2b(v.x);
        x_c[i + 1] = f2b(v.y);
        x_c[i + 2] = f2b(v.z);
        x_c[i + 3] = f2b(v.w);
        return;
    }
    const float* in;
    uint16_t* out;
    int R, W, bx, by;
    if (id < 7168) {
        int tb = id - 4096;
        in = w_qkv; out = wt_qkv; R = 1024; W = 3072;
        bx = tb % 96; by = tb / 96;
    } else {
        int tb = id - 7168;
        in = w_proj; out = wt_proj; R = 1024; W = 1024;
        bx = tb & 31; by = tb >> 5;
    }
    int tx = tid & 31, ty = tid >> 5;
    int c0 = bx * 32, r0 = by * 32;
    #pragma unroll
    for (int i = 0; i < 32; i += 8)
        tile[ty + i][tx] = f2b(in[(size_t)(r0 + ty + i) * W + (c0 + tx)]);
    __syncthreads();
    #pragma unroll
    for (int i = 0; i < 32; i += 8)
        out[(size_t)(c0 + ty + i) * R + (r0 + tx)] = tile[tx][ty + i];
}

// ------- GEMM: C[M,N] = A[M,K] @ Bt[N,K]^T ; bf16 in, fp32 acc -------------
// Counted-vmcnt pipeline (T3+T4): BK=32, THREE LDS buffers, depth-2
// global_load_lds prefetch; never drain vmcnt to 0 in the main loop (m218).
// XOR slot swizzle with pre-swizzled global source. Grid 1D, bijective XCD
// swizzle (nwg % 8 == 0), A-panel-major.
// BN template: 128 (per-wave 64x64, 4 loads/tile) or 64 (per-wave 64x32,
// 3 loads/tile) -- BN=64 doubles the proj grid to 2 blocks/CU.
template <bool OUT_F32, int BN>
__global__ __launch_bounds__(256, 3)
void gemm_bt(const uint16_t* __restrict__ A, const uint16_t* __restrict__ Bt,
             void* __restrict__ Cv, int M, int N, int K) {
    constexpr int NJ = BN / 32;           // per-wave 16-col frags
    constexpr int BUFB = BN * 32;         // u16 per B buffer
    __shared__ uint16_t As[3][128][32];
    __shared__ uint16_t Bs[3][BN][32];
    int tid = threadIdx.x;
    int w = tid >> 6, lane = tid & 63;
    int quad = lane >> 4, l16 = lane & 15;
    int wr = (w >> 1) * 64, wc = (w & 1) * (BN / 2);

    int nwg = gridDim.x;
    int wg = (blockIdx.x & 7) * (nwg >> 3) + (blockIdx.x >> 3);
    int nby = N / BN;
    int row0 = (wg / nby) * 128;
    int col0 = (wg % nby) * BN;

    // A staging: wave w rows w*32+(lane>>2) and +16; phys slot lane&3,
    // pre-swizzled source k-slot (lane&3)^(row&3).
    int sr = w * 32 + (lane >> 2);
    int gscA = ((lane & 3) ^ ((lane >> 2) & 3)) * 8;
    uint16_t* lA0 = &As[0][sr][(lane & 3) * 8];
    const uint16_t* gA = A + (size_t)(row0 + sr) * K + gscA;
    // B staging: BN=128 -> rows sr, sr+16 (2 loads); BN=64 -> row tid>>2 (1).
    int srB = (BN == 128) ? sr : (tid >> 2);
    int gscB = ((lane & 3) ^ (srB & 3)) * 8;
    uint16_t* lB0 = &Bs[0][srB][(lane & 3) * 8];
    const uint16_t* gB = Bt + (size_t)(col0 + srB) * K + gscB;

    floatx4 acc[4][NJ];
    #pragma unroll
    for (int i = 0; i < 4; i++)
        #pragma unroll
        for (int j = 0; j < NJ; j++)
            acc[i][j] = (floatx4){0.f, 0.f, 0.f, 0.f};

#define STAGE3_(bs_, t_)                                                    \
    {                                                                       \
        const uint16_t* ga_ = gA + (size_t)(t_) * 32;                       \
        const uint16_t* gb_ = gB + (size_t)(t_) * 32;                       \
        uint16_t* la_ = lA0 + (bs_) * 4096;                                 \
        uint16_t* lb_ = lB0 + (bs_) * BUFB;                                 \
        glds16(ga_, la_);                                                   \
        glds16(ga_ + 16 * K, la_ + 512);                                    \
        glds16(gb_, lb_);                                                   \
        if constexpr (BN == 128) glds16(gb_ + 16 * K, lb_ + 512);           \
    }

    int NT = K >> 5;                 // K=1024 -> 32 tiles
    STAGE3_(0, 0);
    STAGE3_(1, 1);
    if constexpr (BN == 128)
        asm volatile("s_waitcnt vmcnt(4)" ::: "memory");   // tile 0 resident
    else
        asm volatile("s_waitcnt vmcnt(3)" ::: "memory");
    __builtin_amdgcn_s_barrier();

    const uint16_t* Ab = &As[0][0][0];
    const uint16_t* Bb = &Bs[0][0][0];
    int s = (quad ^ (l16 & 3)) * 8;  // swizzled read slot (loop-invariant)
    int bc = 0, bs = 2;
    for (int t = 0; t < NT; ++t) {
        if (t + 2 < NT) STAGE3_(bs, t + 2);
        __builtin_amdgcn_sched_barrier(0);   // pin stage issue before compute
        const uint16_t* Ac = Ab + bc * 4096;
        const uint16_t* Bc = Bb + bc * BUFB;
        short8 af[4], bfr[NJ];
        #pragma unroll
        for (int i = 0; i < 4; i++)
            af[i] = *(const short8*)&Ac[(wr + i * 16 + l16) * 32 + s];
        #pragma unroll
        for (int j = 0; j < NJ; j++)
            bfr[j] = *(const short8*)&Bc[(wc + j * 16 + l16) * 32 + s];
        #pragma unroll
        for (int i = 0; i < 4; i++)
            #pragma unroll
            for (int j = 0; j < NJ; j++)
                acc[i][j] = __builtin_amdgcn_mfma_f32_16x16x32_bf16(
                    af[i], bfr[j], acc[i][j], 0, 0, 0);
        if (t + 2 < NT) {
            if constexpr (BN == 128)
                asm volatile("s_waitcnt vmcnt(4)" ::: "memory");  // t+1 ready
            else
                asm volatile("s_waitcnt vmcnt(3)" ::: "memory");
        } else {
            asm volatile("s_waitcnt vmcnt(0)" ::: "memory");      // tail drain
        }
        __builtin_amdgcn_s_barrier();
        bc = (bc == 2) ? 0 : bc + 1;
        bs = (bs == 2) ? 0 : bs + 1;
    }
#undef STAGE3_

    #pragma unroll
    for (int i = 0; i < 4; i++) {
        #pragma unroll
        for (int j = 0; j < NJ; j++) {
            int rbase = row0 + wr + i * 16 + quad * 4;
            int cg = col0 + wc + j * 16 + l16;
            #pragma unroll
            for (int r = 0; r < 4; r++) {
                if (OUT_F32)
                    ((float*)Cv)[(size_t)(rbase + r) * N + cg] = acc[i][j][r];
                else
                    ((uint16_t*)Cv)[(size_t)(rbase + r) * N + cg] = f2b(acc[i][j][r]);
            }
        }
    }
}

// ---------------- MFMA flash attention with sink ---------------------------
// STRIP-PER-BLOCK: block (strip,bh), 1024 blocks (3 resident/CU, 46 KB LDS).
// 4 waves each own 16 q-rows of the strip (rows strip*64+w*16) and run
// identical code for strip+1 k-tiles -> perfect wave balance, higher
// occupancy than the old 512-block pair scheme (grid-limited 2/CU).
// Longest strips dispatch first (strip = 31 - id/32); id%8 = bh%8 keeps
// same-head blocks on one XCD L2. log2-space softmax, defer-max (T13,
// THR=8), v_cvt_pk_bf16_f32 P-packing. Per-row numerics identical to r5.
__global__ __launch_bounds__(256, 3)
void attn_mfma(const uint16_t* __restrict__ qkv,
               const float* __restrict__ sink,
               uint16_t* __restrict__ y) {
    __shared__ uint16_t Ks[2][64][72];   // [buf][key][d]   18432 B
    __shared__ uint16_t Vt[2][64][72];   // [buf][d][key]   18432 B (swizzled)
    __shared__ uint16_t Pl[4][16][72];   // per-wave [q][key] 9216 B

    int tid = threadIdx.x;
    int w = tid >> 6, lane = tid & 63;
    int quad = lane >> 4, l16 = lane & 15;

    int id = blockIdx.x;
    int strip = 31 - (id >> 5);         // longest first
    int bh = id & 31;
    int b = bh >> 4, h = bh & 15;
    int q0 = strip * 64 + w * 16;       // this wave's 16 q rows
    int ktiles = strip + 1;

    const uint16_t* qkv_b = qkv + (size_t)b * T_ * 3072;

    // ---- Q fragments: 2 kd, pre-scaled by log2(e)/8 ----
    const float QSC = 0.125f * 1.44269504f;
    short8 qf[2];
    {
        int qrow = q0 + l16;
        #pragma unroll
        for (int kd = 0; kd < 2; kd++) {
            uint4 raw = *(const uint4*)(qkv_b + (size_t)qrow * 3072 + h * 64 +
                                        kd * 32 + quad * 8);
            const uint16_t* rp = (const uint16_t*)&raw;
            short8 f;
            #pragma unroll
            for (int j = 0; j < 8; j++)
                f[j] = (short)f2b(bf2f(rp[j]) * QSC);
            qf[kd] = f;
        }
    }

    float m_s = sink[h] * 1.44269504f;   // log2 space
    float l_s = 1.0f;
    floatx4 acc_o[4];
    #pragma unroll
    for (int dt = 0; dt < 4; dt++)
        acc_o[dt] = (floatx4){0.f, 0.f, 0.f, 0.f};

    // ---- staging map: thread (t2,dg): key rows 2t2,2t2+1, dims dg*8..+7 ----
    int t2 = tid >> 3;
    int dg = tid & 7;
    const uint16_t* kgp = qkv_b + 1024 + h * 64 + (size_t)(2 * t2) * 3072 + dg * 8;
    const uint16_t* vgp = kgp + 1024;
    int vcw = 2 * (t2 ^ (4 * dg));   // swizzled u16 col for V^T key-pair store

    uint4 kr0 = *(const uint4*)(kgp);
    uint4 kr1 = *(const uint4*)(kgp + 3072);
    uint4 vr0 = *(const uint4*)(vgp);
    uint4 vr1 = *(const uint4*)(vgp + 3072);
    // store tile 0 -> buf 0
    {
        *(uint4*)&Ks[0][2 * t2][dg * 8] = kr0;
        *(uint4*)&Ks[0][2 * t2 + 1][dg * 8] = kr1;
        const uint16_t* a0 = (const uint16_t*)&vr0;
        const uint16_t* a1 = (const uint16_t*)&vr1;
        #pragma unroll
        for (int j = 0; j < 8; j++)
            *(uint32_t*)&Vt[0][dg * 8 + j][vcw] =
                (uint32_t)a0[j] | ((uint32_t)a1[j] << 16);
    }
    if (ktiles > 1) {   // preload tile 1
        kr0 = *(const uint4*)(kgp + 64 * 3072);
        kr1 = *(const uint4*)(kgp + 64 * 3072 + 3072);
        vr0 = *(const uint4*)(vgp + 64 * 3072);
        vr1 = *(const uint4*)(vgp + 64 * 3072 + 3072);
    }
    __syncthreads();

    for (int kt = 0; kt < ktiles; kt++) {
        int cur = kt & 1;
        // ---- store prefetched tile kt+1 into the other buffer ----
        if (kt + 1 < ktiles) {
            *(uint4*)&Ks[cur ^ 1][2 * t2][dg * 8] = kr0;
            *(uint4*)&Ks[cur ^ 1][2 * t2 + 1][dg * 8] = kr1;
            const uint16_t* a0 = (const uint16_t*)&vr0;
            const uint16_t* a1 = (const uint16_t*)&vr1;
            #pragma unroll
            for (int j = 0; j < 8; j++)
                *(uint32_t*)&Vt[cur ^ 1][dg * 8 + j][vcw] =
                    (uint32_t)a0[j] | ((uint32_t)a1[j] << 16);
        }
        // ---- issue prefetch of tile kt+2 (lands during this iter) ----
        if (kt + 2 < ktiles) {
            size_t off = (size_t)(kt + 2) * 64 * 3072;
            kr0 = *(const uint4*)(kgp + off);
            kr1 = *(const uint4*)(kgp + off + 3072);
            vr0 = *(const uint4*)(vgp + off);
            vr1 = *(const uint4*)(vgp + off + 3072);
        }
        // ---- K and V fragments ----
        short8 kf[4][2];
        #pragma unroll
        for (int rt = 0; rt < 4; rt++) {
            kf[rt][0] = *(const short8*)&Ks[cur][rt * 16 + l16][quad * 8];
            kf[rt][1] = *(const short8*)&Ks[cur][rt * 16 + l16][32 + quad * 8];
        }
        short8 vf[2][4];
        #pragma unroll
        for (int kb = 0; kb < 2; kb++)
            #pragma unroll
            for (int dt = 0; dt < 4; dt++) {
                int d = dt * 16 + l16;
                int col = 2 * (((kb * 16) + quad * 4) ^ (4 * (d >> 3)));
                vf[kb][dt] = *(const short8*)&Vt[cur][d][col];
            }
        // ---- S^T = K * Q^T : key = rt*16+quad*4+r, q = l16 ----
        floatx4 acc_s[4];
        #pragma unroll
        for (int rt = 0; rt < 4; rt++)
            acc_s[rt] = (floatx4){0.f, 0.f, 0.f, 0.f};
        #pragma unroll
        for (int rt = 0; rt < 4; rt++) {
            acc_s[rt] = __builtin_amdgcn_mfma_f32_16x16x32_bf16(
                kf[rt][0], qf[0], acc_s[rt], 0, 0, 0);
            acc_s[rt] = __builtin_amdgcn_mfma_f32_16x16x32_bf16(
                kf[rt][1], qf[1], acc_s[rt], 0, 0, 0);
        }
        // ---- causal mask: only the diagonal tile ----
        if (kt == strip) {
            int qg = q0 + l16;
            #pragma unroll
            for (int rt = 0; rt < 4; rt++) {
                int kg = kt * 64 + rt * 16 + quad * 4;
                #pragma unroll
                for (int r = 0; r < 4; r++)
                    if (kg + r > qg) acc_s[rt][r] = -1e30f;
            }
        }
        // ---- online softmax in log2 space (q = l16) ----
        float mx = -1e30f;
        #pragma unroll
        for (int rt = 0; rt < 4; rt++)
            #pragma unroll
            for (int r = 0; r < 4; r++) mx = fmaxf(mx, acc_s[rt][r]);
        mx = fmaxf(mx, __shfl_xor(mx, 16));
        mx = fmaxf(mx, __shfl_xor(mx, 32));
        float mold = m_s;
        // T13 defer-max: only rescale when tile max exceeds m by >8
        if (!__all(mx <= mold + 8.0f)) {
            float mnew = fmaxf(mold, mx);
            float alpha = exp2v(mold - mnew);
            m_s = mnew;
            l_s *= alpha;
            #pragma unroll
            for (int r = 0; r < 4; r++) {
                float ar = __shfl(alpha, (lane & 48) | (quad * 4 + r));
                #pragma unroll
                for (int dt = 0; dt < 4; dt++) acc_o[dt][r] *= ar;
            }
        }
        float mcur = m_s;
        float psum = 0.f;
        #pragma unroll
        for (int rt = 0; rt < 4; rt++) {
            float p0 = exp2v(acc_s[rt][0] - mcur);
            float p1 = exp2v(acc_s[rt][1] - mcur);
            float p2 = exp2v(acc_s[rt][2] - mcur);
            float p3 = exp2v(acc_s[rt][3] - mcur);
            psum += (p0 + p1) + (p2 + p3);
            uint2 pk;
            pk.x = cvtpk(p0, p1);
            pk.y = cvtpk(p2, p3);
            *(uint2*)&Pl[w][l16][rt * 16 + quad * 4] = pk;
        }
        psum += __shfl_xor(psum, 16);
        psum += __shfl_xor(psum, 32);
        l_s += psum;
        // ---- O += P * V ----
        #pragma unroll
        for (int kb = 0; kb < 2; kb++) {
            short8 pf = *(const short8*)&Pl[w][l16][kb * 32 + quad * 8];
            #pragma unroll
            for (int dt = 0; dt < 4; dt++)
                acc_o[dt] = __builtin_amdgcn_mfma_f32_16x16x32_bf16(
                    pf, vf[kb][dt], acc_o[dt], 0, 0, 0);
        }
        __syncthreads();
    }

    // ---- epilogue: normalize by l (per-q via in-quad shuffle), store bf16 --
    #pragma unroll
    for (int r = 0; r < 4; r++) {
        float lr = __shfl(l_s, (lane & 48) | (quad * 4 + r));
        float inv = 1.0f / lr;
        int qg = q0 + quad * 4 + r;
        uint16_t* yp = y + (size_t)(b * T_ + qg) * 1024 + h * 64;
        #pragma unroll
        for (int dt = 0; dt < 4; dt++)
            yp[dt * 16 + l16] = f2b(acc_o[dt][r] * inv);
    }
}

extern "C" void kernel_launch(void* const* d_in, const int* in_sizes, int n_in,
                              void* d_out, int out_size, void* d_ws, size_t ws_size,
                              hipStream_t stream) {
    const float* x      = (const float*)d_in[0];  // [B,T,C] fp32
    const float* w_qkv  = (const float*)d_in[1];  // [C, 3HD] fp32
    const float* w_proj = (const float*)d_in[2];  // [HD, C] fp32
    const float* sink   = (const float*)d_in[3];  // [H] fp32
    float* out          = (float*)d_out;          // [B,T,C] fp32

    char* ws = (char*)d_ws;
    uint16_t* wt_qkv  = (uint16_t*)ws;                       // [3072,1024] 6.29 MB
    uint16_t* wt_proj = (uint16_t*)(ws + 6291456);           // [1024,1024] 2.10 MB
    uint16_t* x_c     = (uint16_t*)(ws + 8388608);           // [4096,1024] 8.39 MB
    uint16_t* qkv     = (uint16_t*)(ws + 16777216);          // [4096,3072] 25.17 MB
    uint16_t* yb      = (uint16_t*)(ws + 41943040);          // [4096,1024] 8.39 MB

    // fused prep: canon + both transposes in ONE dispatch
    prep<<<dim3(8192), 256, 0, stream>>>(x, x_c, w_qkv, wt_qkv, w_proj, wt_proj);

    // 1D grids, nwg % 8 == 0 (bijective XCD swizzle inside)
    gemm_bt<false, 128><<<dim3(768), 256, 0, stream>>>(
        x_c, wt_qkv, qkv, 4096, 3072, 1024);

    // strip-per-block grid: id = (31-strip)*32 + bh (longest first; id%8=bh%8)
    attn_mfma<<<dim3(32 * 32), 256, 0, stream>>>(qkv, sink, yb);

    // proj: 128x64 tiles -> 512 blocks = 2 blocks/CU (was 256 = 1/CU)
    gemm_bt<true, 64><<<dim3(512), 256, 0, stream>>>(
        yb, wt_proj, out, 4096, 1024, 1024);
}